// Round 16
// baseline (885.563 us; speedup 1.0000x reference)
//
#include <hip/hip_runtime.h>
#include <stdint.h>

#define BATCH   4096
#define DMODEL  768
#define DSAE    32768
#define KTOP    32
#define CAP     512          // candidate list capacity per row
#define WCAP    96           // exact-rescore window capacity
#define THR_CAND 2.5f        // static candidate threshold (z ~ N(0,1), v32 in [2.8,3.3])
#define WINDOW   0.08f       // rescore window half-width (> 2x max GEMM error 0.031)
#define VGUARD   2.66f       // min v32 for candidate path (= THR_CAND + 2*WINDOW)

typedef _Float16 f16;
typedef _Float16 f16x4 __attribute__((ext_vector_type(4)));
typedef _Float16 f16x8 __attribute__((ext_vector_type(8)));
typedef float    f32x4 __attribute__((ext_vector_type(4)));
typedef unsigned int uint;

// ---------------------------------------------------------------------------
// x (fp32) -> xh (fp16); also zeroes the per-row candidate counters
// ---------------------------------------------------------------------------
__global__ __launch_bounds__(256) void k_split_x(const float* __restrict__ x,
                                                 f16* __restrict__ xh,
                                                 uint* __restrict__ cnt) {
    int i = blockIdx.x * 256 + threadIdx.x;   // 786432 float4 quads
    if (i < BATCH) cnt[i] = 0;
    float4 v = ((const float4*)x)[i];
    f16x4 h;
    h[0] = (f16)v.x; h[1] = (f16)v.y; h[2] = (f16)v.z; h[3] = (f16)v.w;
    ((f16x4*)xh)[i] = h;
}

// ---------------------------------------------------------------------------
// Transpose W_enc [768][32768] -> whT fp16 [32768][768] + WT fp32 [32768][768]
// ---------------------------------------------------------------------------
__global__ __launch_bounds__(256) void k_split_wT(const float* __restrict__ W,
                                                  f16* __restrict__ whT,
                                                  float* __restrict__ WT) {
    __shared__ float T[32][33];
    int n0 = blockIdx.x * 32, k0 = blockIdx.y * 32;
    int tx = threadIdx.x, ty = threadIdx.y;   // (32, 8)
#pragma unroll
    for (int i = 0; i < 4; ++i)
        T[ty + i * 8][tx] = W[(size_t)(k0 + ty + i * 8) * DSAE + n0 + tx];
    __syncthreads();
#pragma unroll
    for (int i = 0; i < 4; ++i) {
        float v = T[tx][ty + i * 8];          // = W[k0+tx][n0+ty+i*8]
        size_t o = (size_t)(n0 + ty + i * 8) * DMODEL + k0 + tx;
        whT[o] = (f16)v;
        WT[o]  = v;
    }
}

// ---------------------------------------------------------------------------
// fp16 MFMA GEMM: z_pre = x @ W_enc + b_enc   (R13 structure, best measured)
// 128x128 tile, BK=32, dbuf + counted vmcnt, 8x8-chunked per-XCD traversal
// (staging L2-resident). __launch_bounds__(256,5): 5 blocks/CU (LDS 32KB
// fits 5x, VGPR capped at 102 >= 68 used) — TLP hides the per-block
// barrier/vmcnt stalls that in-block pipelining (R12/R14) couldn't.
// ---------------------------------------------------------------------------
__device__ __forceinline__ void gl_lds16(const f16* g, f16* l) {
    __builtin_amdgcn_global_load_lds(
        (const __attribute__((address_space(1))) uint32_t*)g,
        (__attribute__((address_space(3))) uint32_t*)l,
        16, 0, 0);
}

#define BUFOFF (128 * 32)    // f16 elements per LDS buffer

__global__ __launch_bounds__(256, 5) void k_gemm(
        const f16* __restrict__ Ahg, const f16* __restrict__ Bhg,
        const float* __restrict__ benc, float* __restrict__ zpre,
        uint* __restrict__ cnt, float* __restrict__ candV,
        int* __restrict__ candI, float* __restrict__ zsp) {
    __shared__ f16 Ah[2][128][32];
    __shared__ f16 Bh[2][128][32];

    // 8192 blocks = 8 XCDs x (16 chunks of 8bm x 8bn). Bijective:
    int bid   = blockIdx.x;
    int xcd   = bid & 7;
    int k     = bid >> 3;
    int chunk = k >> 6;
    int g     = k & 63;
    int bm    = (chunk & 3) * 8 + (g & 7);
    int bn    = xcd * 32 + (chunk >> 2) * 8 + (g >> 3);
    int brow  = bm * 128, bcol = bn * 128;

    int t = threadIdx.x, lane = t & 63, w = t >> 6;
    int wr = w >> 1, wc = w & 1;

    int kk0 = (t & 3) * 8;
    const f16* pA0 = Ahg + (size_t)(brow + (t >> 2)) * DMODEL + kk0;
    const f16* pA1 = Ahg + (size_t)(brow + (t >> 2) + 64) * DMODEL + kk0;
    const f16* pB0 = Bhg + (size_t)(bcol + (t >> 2)) * DMODEL + kk0;
    const f16* pB1 = Bhg + (size_t)(bcol + (t >> 2) + 64) * DMODEL + kk0;
    f16* lA0 = &Ah[0][0][0] + t * 8;
    f16* lA1 = &Ah[0][0][0] + (t + 256) * 8;
    f16* lB0 = &Bh[0][0][0] + t * 8;
    f16* lB1 = &Bh[0][0][0] + (t + 256) * 8;

    f32x4 acc[4][4];
    f32x4 vzero = {0.0f, 0.0f, 0.0f, 0.0f};
#pragma unroll
    for (int m = 0; m < 4; ++m)
#pragma unroll
        for (int n = 0; n < 4; ++n) acc[m][n] = vzero;

    int ar = wr * 64 + (lane & 15);
    int bc = wc * 64 + (lane & 15);
    int kk = (lane >> 4) * 8;

    // prologue: stage steps 0 (buf0) and 1 (buf1) -> 8 loads in flight
    gl_lds16(pA0, lA0);
    gl_lds16(pA1, lA1);
    gl_lds16(pB0, lB0);
    gl_lds16(pB1, lB1);
    gl_lds16(pA0 + 32, lA0 + BUFOFF);
    gl_lds16(pA1 + 32, lA1 + BUFOFF);
    gl_lds16(pB0 + 32, lB0 + BUFOFF);
    gl_lds16(pB1 + 32, lB1 + BUFOFF);

    for (int ks = 0; ks < 23; ++ks) {
        int cur = ks & 1;
        asm volatile("s_waitcnt vmcnt(4)" ::: "memory");
        __builtin_amdgcn_s_barrier();          // step-ks data visible to all

        f16x8 a[4], bfr[4];
#pragma unroll
        for (int m = 0; m < 4; ++m) a[m] = *(const f16x8*)&Ah[cur][ar + m * 16][kk];
#pragma unroll
        for (int n = 0; n < 4; ++n) bfr[n] = *(const f16x8*)&Bh[cur][bc + n * 16][kk];
#pragma unroll
        for (int m = 0; m < 4; ++m)
#pragma unroll
            for (int n = 0; n < 4; ++n)
                acc[m][n] = __builtin_amdgcn_mfma_f32_16x16x32_f16(a[m], bfr[n], acc[m][n], 0, 0, 0);

        __builtin_amdgcn_s_barrier();          // all waves done reading buf[cur]
        __builtin_amdgcn_sched_barrier(0);     // keep stages below the barrier
        if (ks < 22) {
            int ko = (ks + 2) * 32;
            int bo = cur * BUFOFF;             // restage the just-freed buffer
            gl_lds16(pA0 + ko, lA0 + bo);
            gl_lds16(pA1 + ko, lA1 + bo);
            gl_lds16(pB0 + ko, lB0 + bo);
            gl_lds16(pB1 + ko, lB1 + bo);
        }
    }
    // peeled last step (ks=23, buf1)
    asm volatile("s_waitcnt vmcnt(0)" ::: "memory");
    __builtin_amdgcn_s_barrier();
    {
        f16x8 a[4], bfr[4];
#pragma unroll
        for (int m = 0; m < 4; ++m) a[m] = *(const f16x8*)&Ah[1][ar + m * 16][kk];
#pragma unroll
        for (int n = 0; n < 4; ++n) bfr[n] = *(const f16x8*)&Bh[1][bc + n * 16][kk];
#pragma unroll
        for (int m = 0; m < 4; ++m)
#pragma unroll
            for (int n = 0; n < 4; ++n)
                acc[m][n] = __builtin_amdgcn_mfma_f32_16x16x32_f16(a[m], bfr[n], acc[m][n], 0, 0, 0);
    }

    // zero-fill this block's 128x128 z_sparse tile (stores drain under epilogue)
    {
        float4 z4 = make_float4(0.0f, 0.0f, 0.0f, 0.0f);
#pragma unroll
        for (int k2 = 0; k2 < 16; ++k2) {
            int idx = t + k2 * 256;
            int row = idx >> 5, c4 = idx & 31;
            ((float4*)(zsp + (size_t)(brow + row) * DSAE + bcol))[c4] = z4;
        }
    }

    // epilogue (C/D layout: col = lane&15, row = (lane>>4)*4 + j)
#pragma unroll
    for (int n = 0; n < 4; ++n) {
        int col = bcol + wc * 64 + n * 16 + (lane & 15);
        float be = benc[col];
#pragma unroll
        for (int m = 0; m < 4; ++m) {
            int r0 = brow + wr * 64 + m * 16 + (lane >> 4) * 4;
#pragma unroll
            for (int j = 0; j < 4; ++j) {
                float zv = acc[m][n][j] + be;
                zpre[(size_t)(r0 + j) * DSAE + col] = zv;
                if (zv >= THR_CAND) {
                    int row = r0 + j;
                    uint p = atomicAdd(&cnt[row], 1u);
                    if (p < CAP) {
                        candV[(size_t)row * CAP + p] = zv;
                        candI[(size_t)row * CAP + p] = col;
                    }
                }
            }
        }
    }
}

// ---------------------------------------------------------------------------
// fp64 rescore of one feature row against x_s (summation tree fixed:
// lane sums elems [12*lane, 12*lane+12) in order, then shfl tree 32..1)
// ---------------------------------------------------------------------------
__device__ __forceinline__ double rescore_row(const float* __restrict__ WT,
                                              const float* __restrict__ x_s,
                                              int feat, int lane) {
    const float4* wrow = (const float4*)(WT + (size_t)feat * DMODEL) + lane * 3;
    const float4* xr = ((const float4*)x_s) + lane * 3;
    double acc = 0.0;
#pragma unroll
    for (int q = 0; q < 3; ++q) {
        float4 wq = wrow[q], xq = xr[q];
        acc += (double)wq.x * xq.x;
        acc += (double)wq.y * xq.y;
        acc += (double)wq.z * xq.z;
        acc += (double)wq.w * xq.w;
    }
#pragma unroll
    for (int off = 32; off >= 1; off >>= 1) acc += __shfl_down(acc, off);
    return acc;
}

// ---------------------------------------------------------------------------
// Fused back half, fast path only. 256 threads/row. Candidate rank -> v32 ->
// window -> fp64 rescore -> exact rank -> scatter -> decode.
// z_sparse rows are pre-zeroed by k_gemm. ok[b]=0 defers to fallback.
// ---------------------------------------------------------------------------
__global__ __launch_bounds__(256) void k_fused(
        const float* __restrict__ x, const float* __restrict__ WT,
        const float* __restrict__ benc, const uint* __restrict__ cnt,
        const float* __restrict__ candV, const int* __restrict__ candI,
        const float* __restrict__ Wdec, const float* __restrict__ bdec,
        float* __restrict__ zsp, float* __restrict__ xrec,
        uint* __restrict__ ok) {
    int b = blockIdx.x, t = threadIdx.x;
    __shared__ float  cv[CAP];
    __shared__ int    ci[CAP];
    __shared__ float  wv[WCAP];
    __shared__ int    wi[WCAP];
    __shared__ double wex[WCAP];
    __shared__ float  x_s[DMODEL];
    __shared__ float  sv[KTOP];
    __shared__ int    si[KTOP];
    __shared__ uint   s_nw, s_v32b;

    if (t < DMODEL / 4)
        ((float4*)x_s)[t] = ((const float4*)(x + (size_t)b * DMODEL))[t];

    uint nc = cnt[b];
    int bad = (nc < KTOP) || (nc > CAP);
    if (t == 0) s_nw = 0;
    if (!bad) {
        for (uint i = t; i < nc; i += 256) {
            cv[i] = candV[(size_t)b * CAP + i];
            ci[i] = candI[(size_t)b * CAP + i];
        }
    }
    __syncthreads();

    if (!bad) {
        // rank candidates by computed value (desc, idx asc) -> find v32
        for (uint i = t; i < nc; i += 256) {
            float mv = cv[i]; int mi = ci[i];
            int rank = 0;
            for (uint j = 0; j < nc; ++j) {
                float oj = cv[j];
                rank += (oj > mv) || (oj == mv && ci[j] < mi);
            }
            if (rank == KTOP - 1) s_v32b = __float_as_uint(mv);
        }
        __syncthreads();
        float v32 = __uint_as_float(s_v32b);
        if (v32 < VGUARD) {
            bad = 1;
        } else {
            float vlo = v32 - WINDOW;
            for (uint i = t; i < nc; i += 256) {
                if (cv[i] >= vlo) {
                    uint p = atomicAdd(&s_nw, 1u);
                    if (p < WCAP) { wv[p] = cv[i]; wi[p] = ci[i]; }
                }
            }
            __syncthreads();
            if (s_nw > WCAP) bad = 1;
        }
    }
    __syncthreads();
    uint nw = s_nw;

    if (!bad) {
        // fp64 rescore: wave (t>>6) handles window items wid, wid+4, ...
        int wid = t >> 6, lane = t & 63;
        for (uint c = (uint)wid; c < nw; c += 4) {
            double acc = rescore_row(WT, x_s, wi[c], lane);
            if (lane == 0) wex[c] = acc + (double)benc[wi[c]];
        }
        __syncthreads();
        // exact ranking within window; winners = ranks 0..31
        if (t < (int)nw) {
            double my = wex[t];
            int myi = wi[t];
            int rank = 0;
            for (uint c = 0; c < nw; ++c)
                rank += (wex[c] > my) || (wex[c] == my && wi[c] < myi);
            if (rank < KTOP) { sv[rank] = wv[t]; si[rank] = myi; }
        }
    }
    __syncthreads();

    if (t == 0) ok[b] = bad ? 0u : 1u;
    if (bad) return;   // k_fallback completes this row (row zeroed by k_gemm)

    if (t < KTOP) zsp[(size_t)b * DSAE + si[t]] = sv[t];

    // decode: x_recon[b] = sum_s sv[s] * W_dec[si[s]] + b_dec
    float a0 = bdec[t], a1 = bdec[t + 256], a2 = bdec[t + 512];
#pragma unroll 8
    for (int s = 0; s < KTOP; ++s) {
        float vv = sv[s];
        const float* wr2 = Wdec + (size_t)si[s] * DMODEL + t;
        a0 += vv * wr2[0];
        a1 += vv * wr2[256];
        a2 += vv * wr2[512];
    }
    float* pr = xrec + (size_t)b * DMODEL;
    pr[t] = a0; pr[t + 256] = a1; pr[t + 512] = a2;
}

// ---------------------------------------------------------------------------
// radix select helper (64-group suffix-sum over 2048-bin histogram)
// ---------------------------------------------------------------------------
__device__ __forceinline__ uint2 radix_step(uint* hist, uint need, uint* s_res) {
    int t = threadIdx.x;
    if (t < 64) {
        uint s = 0;
#pragma unroll
        for (int j = 0; j < 32; ++j) s += hist[t * 32 + j];
        uint suf = s;
#pragma unroll
        for (int off = 1; off < 64; off <<= 1) {
            uint o = __shfl_down(suf, off);
            if (t + off < 64) suf += o;
        }
        unsigned long long m = __ballot(suf >= need);
        int L = 63 - __builtin_clzll(m);
        uint aboveg = (L == 63) ? 0u : __shfl(suf, L + 1);
        uint h = (t < 32) ? hist[L * 32 + t] : 0u;
        uint suf2 = h;
#pragma unroll
        for (int off = 1; off < 32; off <<= 1) {
            uint o = __shfl_down(suf2, off);
            if (t + off < 32) suf2 += o;
        }
        suf2 += aboveg;
        unsigned long long m2 = __ballot((t < 32) && (suf2 >= need)) & 0xffffffffull;
        int j = 31 - __builtin_clz((uint)m2);
        uint above = (j == 31) ? aboveg : __shfl(suf2, j + 1);
        if (t == 0) { s_res[0] = (uint)(L * 32 + j); s_res[1] = above; }
    }
    __syncthreads();
    uint2 r; r.x = s_res[0]; r.y = s_res[1];
    __syncthreads();
    return r;
}

// ---------------------------------------------------------------------------
// Fallback for rows where the candidate fast path failed (statistically ~0):
// full-row radix select + rescore (or ultra tie-break) + scatter + decode.
// Early-exits when ok[b]==1.
// ---------------------------------------------------------------------------
__global__ __launch_bounds__(1024) void k_fallback(
        const float* __restrict__ zpre, const float* __restrict__ x,
        const float* __restrict__ WT, const float* __restrict__ benc,
        const float* __restrict__ Wdec, const float* __restrict__ bdec,
        const uint* __restrict__ ok, float* __restrict__ zsp,
        float* __restrict__ xrec) {
    int b = blockIdx.x, t = threadIdx.x;
    if (ok[b]) return;

    __shared__ uint   hist[2048];
    __shared__ uint   s_res[2];
    __shared__ uint   s_wsum[16];
    __shared__ uint   s_total;
    __shared__ uint   s_nw;
    __shared__ float  x_s[DMODEL];
    __shared__ float  wv[WCAP];
    __shared__ int    wi[WCAP];
    __shared__ double wex[WCAP];
    __shared__ float  s_val[KTOP];
    __shared__ int    s_idx[KTOP];

    const float4* rp = (const float4*)(zpre + (size_t)b * DSAE + t * 32);
    float v[32];
#pragma unroll
    for (int i = 0; i < 8; ++i) {
        float4 q = rp[i];
        v[4 * i + 0] = fmaxf(q.x, 0.0f);
        v[4 * i + 1] = fmaxf(q.y, 0.0f);
        v[4 * i + 2] = fmaxf(q.z, 0.0f);
        v[4 * i + 3] = fmaxf(q.w, 0.0f);
    }
    if (t < DMODEL / 4) ((float4*)x_s)[t] = ((const float4*)(x + (size_t)b * DMODEL))[t];
    if (t == 0) s_nw = 0;

    hist[t] = 0; hist[t + 1024] = 0;
    __syncthreads();
#pragma unroll
    for (int i = 0; i < 32; ++i) atomicAdd(&hist[__float_as_uint(v[i]) >> 21], 1u);
    __syncthreads();
    uint2 rA = radix_step(hist, KTOP, s_res);
    uint B1 = rA.x, GA = rA.y;

    hist[t] = 0; hist[t + 1024] = 0;
    __syncthreads();
#pragma unroll
    for (int i = 0; i < 32; ++i) {
        uint bi = __float_as_uint(v[i]);
        if ((bi >> 21) == B1) atomicAdd(&hist[(bi >> 10) & 2047u], 1u);
    }
    __syncthreads();
    uint needB = KTOP - GA;
    uint2 rB = radix_step(hist, needB, s_res);
    uint B2 = rB.x, GB = rB.y;

    hist[t] = 0; hist[t + 1024] = 0;
    __syncthreads();
    uint hi21 = (B1 << 11) | B2;
#pragma unroll
    for (int i = 0; i < 32; ++i) {
        uint bi = __float_as_uint(v[i]);
        if ((bi >> 10) == hi21) atomicAdd(&hist[bi & 1023u], 1u);
    }
    __syncthreads();
    uint needC = needB - GB;
    uint2 rC = radix_step(hist, needC, s_res);
    uint tbits = (hi21 << 10) | rC.x;
    float v32b = __uint_as_float(tbits);

    int ultra = 0;
    if (v32b > 0.04f) {
        float vlo = v32b - WINDOW;
#pragma unroll
        for (int i = 0; i < 32; ++i) {
            if (v[i] >= vlo) {
                uint p = atomicAdd(&s_nw, 1u);
                if (p < WCAP) { wv[p] = v[i]; wi[p] = t * 32 + i; }
            }
        }
    }
    __syncthreads();
    uint nw = s_nw;

    if (v32b <= 0.04f || nw > WCAP) {
        // ultra-fallback: stable tiebreak on computed values
        ultra = 1;
        uint cgt = 0, ceq = 0;
#pragma unroll
        for (int i = 0; i < 32; ++i) {
            uint bi = __float_as_uint(v[i]);
            if (bi > tbits) cgt++;
            else if (bi == tbits) ceq++;
        }
        uint packed = cgt | (ceq << 16);
        int wid = t >> 6, lane = t & 63;
        uint incl = packed;
#pragma unroll
        for (int off = 1; off < 64; off <<= 1) {
            uint o = __shfl_up(incl, off);
            if (lane >= off) incl += o;
        }
        if (lane == 63) s_wsum[wid] = incl;
        __syncthreads();
        if (t == 0) {
            uint run = 0;
#pragma unroll
            for (int w2 = 0; w2 < 16; ++w2) { uint x2 = s_wsum[w2]; s_wsum[w2] = run; run += x2; }
            s_total = run;
        }
        __syncthreads();
        uint base = (incl - packed) + s_wsum[wid];
        uint grk = base & 0xffffu;
        uint erk = base >> 16;
        uint total_gt = s_total & 0xffffu;
        uint need_eq = KTOP - total_gt;
#pragma unroll
        for (int i = 0; i < 32; ++i) {
            uint bi = __float_as_uint(v[i]);
            if (bi > tbits) {
                uint s = grk++;
                s_val[s] = v[i]; s_idx[s] = t * 32 + i;
            } else if (bi == tbits) {
                uint r = erk++;
                if (r < need_eq) {
                    uint s = total_gt + r;
                    s_val[s] = v[i]; s_idx[s] = t * 32 + i;
                }
            }
        }
    }
    __syncthreads();

    if (!ultra) {
        int wid = t >> 6, lane = t & 63;
        for (uint c = (uint)wid; c < nw; c += 16) {
            double acc = rescore_row(WT, x_s, wi[c], lane);
            if (lane == 0) wex[c] = acc + (double)benc[wi[c]];
        }
        __syncthreads();
        if (t < (int)nw) {
            double my = wex[t];
            int myi = wi[t];
            int rank = 0;
            for (uint c = 0; c < nw; ++c)
                rank += (wex[c] > my) || (wex[c] == my && wi[c] < myi);
            if (rank < KTOP) { s_val[rank] = wv[t]; s_idx[rank] = myi; }
        }
        __syncthreads();
    }

    // scatter (row pre-zeroed by k_gemm) + decode
    if (t < KTOP) zsp[(size_t)b * DSAE + s_idx[t]] = s_val[t];
    if (t < DMODEL) {
        float a = bdec[t];
#pragma unroll 8
        for (int s2 = 0; s2 < KTOP; ++s2)
            a += s_val[s2] * Wdec[(size_t)s_idx[s2] * DMODEL + t];
        xrec[(size_t)b * DMODEL + t] = a;
    }
}

// ---------------------------------------------------------------------------
extern "C" void kernel_launch(void* const* d_in, const int* in_sizes, int n_in,
                              void* d_out, int out_size, void* d_ws, size_t ws_size,
                              hipStream_t stream) {
    (void)in_sizes; (void)n_in; (void)out_size; (void)ws_size;
    const float* x     = (const float*)d_in[0];
    const float* W_enc = (const float*)d_in[1];
    const float* b_enc = (const float*)d_in[2];
    const float* W_dec = (const float*)d_in[3];
    const float* b_dec = (const float*)d_in[4];

    float* xrec = (float*)d_out;                       // [4096][768]
    float* zsp  = xrec + (size_t)BATCH * DMODEL;       // [4096][32768]
    float* zpre = zsp + (size_t)BATCH * DSAE;          // [4096][32768]

    // Scratch in d_ws (~4.3 GB per harness poison fills; 176 MiB used)
    char*  ws    = (char*)d_ws;
    uint*  cnt   = (uint*)ws;                          //  16 KiB @ 0
    uint*  okf   = (uint*)(ws + (256u << 10));         //  16 KiB @ 256K
    float* candV = (float*)(ws + (1u   << 20));        //   8 MiB @ 1M
    int*   candI = (int*)  (ws + (10u  << 20));        //   8 MiB @ 10M
    f16*   xh    = (f16*)  (ws + (20u  << 20));        //   6 MiB @ 20M
    f16*   whT   = (f16*)  (ws + (28u  << 20));        //  48 MiB @ 28M
    float* WT    = (float*)(ws + (80u  << 20));        //  96 MiB @ 80M (end 176M)

    k_split_x<<<3072, 256, 0, stream>>>(x, xh, cnt);
    dim3 gw(1024, 24), tw(32, 8);
    k_split_wT<<<gw, tw, 0, stream>>>(W_enc, whT, WT);
    k_gemm<<<8192, 256, 0, stream>>>(xh, whT, b_enc, zpre, cnt, candV, candI, zsp);
    k_fused<<<4096, 256, 0, stream>>>(x, WT, b_enc, cnt, candV, candI,
                                      W_dec, b_dec, zsp, xrec, okf);
    k_fallback<<<4096, 1024, 0, stream>>>(zpre, x, WT, b_enc, W_dec, b_dec,
                                          okf, zsp, xrec);
}

// Round 17
// 735.930 us; speedup vs baseline: 1.2033x; 1.2033x over previous
//
#include <hip/hip_runtime.h>
#include <stdint.h>

#define BATCH   4096
#define DMODEL  768
#define DSAE    32768
#define KTOP    32
#define CAP     512          // candidate list capacity per row
#define WCAP    96           // exact-rescore window capacity
#define THR_CAND 2.5f        // static candidate threshold (z ~ N(0,1), v32 in [2.8,3.3])
#define WINDOW   0.08f       // rescore window half-width (> 2x max GEMM error 0.031)
#define VGUARD   2.66f       // min v32 for candidate path (= THR_CAND + 2*WINDOW)

typedef _Float16 f16;
typedef _Float16 f16x4 __attribute__((ext_vector_type(4)));
typedef _Float16 f16x8 __attribute__((ext_vector_type(8)));
typedef float    f32x4 __attribute__((ext_vector_type(4)));
typedef unsigned int uint;

// ---------------------------------------------------------------------------
// x (fp32) -> xh (fp16); also zeroes the per-row candidate counters
// ---------------------------------------------------------------------------
__global__ __launch_bounds__(256) void k_split_x(const float* __restrict__ x,
                                                 f16* __restrict__ xh,
                                                 uint* __restrict__ cnt) {
    int i = blockIdx.x * 256 + threadIdx.x;   // 786432 float4 quads
    if (i < BATCH) cnt[i] = 0;
    float4 v = ((const float4*)x)[i];
    f16x4 h;
    h[0] = (f16)v.x; h[1] = (f16)v.y; h[2] = (f16)v.z; h[3] = (f16)v.w;
    ((f16x4*)xh)[i] = h;
}

// ---------------------------------------------------------------------------
// Transpose W_enc [768][32768] -> whT fp16 [32768][768] + WT fp32 [32768][768]
// ---------------------------------------------------------------------------
__global__ __launch_bounds__(256) void k_split_wT(const float* __restrict__ W,
                                                  f16* __restrict__ whT,
                                                  float* __restrict__ WT) {
    __shared__ float T[32][33];
    int n0 = blockIdx.x * 32, k0 = blockIdx.y * 32;
    int tx = threadIdx.x, ty = threadIdx.y;   // (32, 8)
#pragma unroll
    for (int i = 0; i < 4; ++i)
        T[ty + i * 8][tx] = W[(size_t)(k0 + ty + i * 8) * DSAE + n0 + tx];
    __syncthreads();
#pragma unroll
    for (int i = 0; i < 4; ++i) {
        float v = T[tx][ty + i * 8];          // = W[k0+tx][n0+ty+i*8]
        size_t o = (size_t)(n0 + ty + i * 8) * DMODEL + k0 + tx;
        whT[o] = (f16)v;
        WT[o]  = v;
    }
}

// ---------------------------------------------------------------------------
// fp16 MFMA GEMM: z_pre = x @ W_enc + b_enc   (R13 structure, best measured)
// 128x128 tile, BK=32, dbuf + counted vmcnt, 8x8-chunked per-XCD traversal
// (staging L2-resident). __launch_bounds__(256,4): 4 blocks/CU (LDS 128KB
// fits, VGPR budget 128 >= ~68+acc used, NO spill — R16's (256,5) squeezed
// to 48 VGPR and spilled the accumulator, regressing).
// ---------------------------------------------------------------------------
__device__ __forceinline__ void gl_lds16(const f16* g, f16* l) {
    __builtin_amdgcn_global_load_lds(
        (const __attribute__((address_space(1))) uint32_t*)g,
        (__attribute__((address_space(3))) uint32_t*)l,
        16, 0, 0);
}

#define BUFOFF (128 * 32)    // f16 elements per LDS buffer

__global__ __launch_bounds__(256, 4) void k_gemm(
        const f16* __restrict__ Ahg, const f16* __restrict__ Bhg,
        const float* __restrict__ benc, float* __restrict__ zpre,
        uint* __restrict__ cnt, float* __restrict__ candV,
        int* __restrict__ candI, float* __restrict__ zsp) {
    __shared__ f16 Ah[2][128][32];
    __shared__ f16 Bh[2][128][32];

    // 8192 blocks = 8 XCDs x (16 chunks of 8bm x 8bn). Bijective:
    int bid   = blockIdx.x;
    int xcd   = bid & 7;
    int k     = bid >> 3;
    int chunk = k >> 6;
    int g     = k & 63;
    int bm    = (chunk & 3) * 8 + (g & 7);
    int bn    = xcd * 32 + (chunk >> 2) * 8 + (g >> 3);
    int brow  = bm * 128, bcol = bn * 128;

    int t = threadIdx.x, lane = t & 63, w = t >> 6;
    int wr = w >> 1, wc = w & 1;

    int kk0 = (t & 3) * 8;
    const f16* pA0 = Ahg + (size_t)(brow + (t >> 2)) * DMODEL + kk0;
    const f16* pA1 = Ahg + (size_t)(brow + (t >> 2) + 64) * DMODEL + kk0;
    const f16* pB0 = Bhg + (size_t)(bcol + (t >> 2)) * DMODEL + kk0;
    const f16* pB1 = Bhg + (size_t)(bcol + (t >> 2) + 64) * DMODEL + kk0;
    f16* lA0 = &Ah[0][0][0] + t * 8;
    f16* lA1 = &Ah[0][0][0] + (t + 256) * 8;
    f16* lB0 = &Bh[0][0][0] + t * 8;
    f16* lB1 = &Bh[0][0][0] + (t + 256) * 8;

    f32x4 acc[4][4];
    f32x4 vzero = {0.0f, 0.0f, 0.0f, 0.0f};
#pragma unroll
    for (int m = 0; m < 4; ++m)
#pragma unroll
        for (int n = 0; n < 4; ++n) acc[m][n] = vzero;

    int ar = wr * 64 + (lane & 15);
    int bc = wc * 64 + (lane & 15);
    int kk = (lane >> 4) * 8;

    // prologue: stage steps 0 (buf0) and 1 (buf1) -> 8 loads in flight
    gl_lds16(pA0, lA0);
    gl_lds16(pA1, lA1);
    gl_lds16(pB0, lB0);
    gl_lds16(pB1, lB1);
    gl_lds16(pA0 + 32, lA0 + BUFOFF);
    gl_lds16(pA1 + 32, lA1 + BUFOFF);
    gl_lds16(pB0 + 32, lB0 + BUFOFF);
    gl_lds16(pB1 + 32, lB1 + BUFOFF);

    for (int ks = 0; ks < 23; ++ks) {
        int cur = ks & 1;
        asm volatile("s_waitcnt vmcnt(4)" ::: "memory");
        __builtin_amdgcn_s_barrier();          // step-ks data visible to all

        f16x8 a[4], bfr[4];
#pragma unroll
        for (int m = 0; m < 4; ++m) a[m] = *(const f16x8*)&Ah[cur][ar + m * 16][kk];
#pragma unroll
        for (int n = 0; n < 4; ++n) bfr[n] = *(const f16x8*)&Bh[cur][bc + n * 16][kk];
#pragma unroll
        for (int m = 0; m < 4; ++m)
#pragma unroll
            for (int n = 0; n < 4; ++n)
                acc[m][n] = __builtin_amdgcn_mfma_f32_16x16x32_f16(a[m], bfr[n], acc[m][n], 0, 0, 0);

        __builtin_amdgcn_s_barrier();          // all waves done reading buf[cur]
        __builtin_amdgcn_sched_barrier(0);     // keep stages below the barrier
        if (ks < 22) {
            int ko = (ks + 2) * 32;
            int bo = cur * BUFOFF;             // restage the just-freed buffer
            gl_lds16(pA0 + ko, lA0 + bo);
            gl_lds16(pA1 + ko, lA1 + bo);
            gl_lds16(pB0 + ko, lB0 + bo);
            gl_lds16(pB1 + ko, lB1 + bo);
        }
    }
    // peeled last step (ks=23, buf1)
    asm volatile("s_waitcnt vmcnt(0)" ::: "memory");
    __builtin_amdgcn_s_barrier();
    {
        f16x8 a[4], bfr[4];
#pragma unroll
        for (int m = 0; m < 4; ++m) a[m] = *(const f16x8*)&Ah[1][ar + m * 16][kk];
#pragma unroll
        for (int n = 0; n < 4; ++n) bfr[n] = *(const f16x8*)&Bh[1][bc + n * 16][kk];
#pragma unroll
        for (int m = 0; m < 4; ++m)
#pragma unroll
            for (int n = 0; n < 4; ++n)
                acc[m][n] = __builtin_amdgcn_mfma_f32_16x16x32_f16(a[m], bfr[n], acc[m][n], 0, 0, 0);
    }

    // zero-fill this block's 128x128 z_sparse tile (stores drain under epilogue)
    {
        float4 z4 = make_float4(0.0f, 0.0f, 0.0f, 0.0f);
#pragma unroll
        for (int k2 = 0; k2 < 16; ++k2) {
            int idx = t + k2 * 256;
            int row = idx >> 5, c4 = idx & 31;
            ((float4*)(zsp + (size_t)(brow + row) * DSAE + bcol))[c4] = z4;
        }
    }

    // epilogue (C/D layout: col = lane&15, row = (lane>>4)*4 + j)
#pragma unroll
    for (int n = 0; n < 4; ++n) {
        int col = bcol + wc * 64 + n * 16 + (lane & 15);
        float be = benc[col];
#pragma unroll
        for (int m = 0; m < 4; ++m) {
            int r0 = brow + wr * 64 + m * 16 + (lane >> 4) * 4;
#pragma unroll
            for (int j = 0; j < 4; ++j) {
                float zv = acc[m][n][j] + be;
                zpre[(size_t)(r0 + j) * DSAE + col] = zv;
                if (zv >= THR_CAND) {
                    int row = r0 + j;
                    uint p = atomicAdd(&cnt[row], 1u);
                    if (p < CAP) {
                        candV[(size_t)row * CAP + p] = zv;
                        candI[(size_t)row * CAP + p] = col;
                    }
                }
            }
        }
    }
}

// ---------------------------------------------------------------------------
// fp64 rescore of one feature row against x_s (summation tree fixed:
// lane sums elems [12*lane, 12*lane+12) in order, then shfl tree 32..1)
// ---------------------------------------------------------------------------
__device__ __forceinline__ double rescore_row(const float* __restrict__ WT,
                                              const float* __restrict__ x_s,
                                              int feat, int lane) {
    const float4* wrow = (const float4*)(WT + (size_t)feat * DMODEL) + lane * 3;
    const float4* xr = ((const float4*)x_s) + lane * 3;
    double acc = 0.0;
#pragma unroll
    for (int q = 0; q < 3; ++q) {
        float4 wq = wrow[q], xq = xr[q];
        acc += (double)wq.x * xq.x;
        acc += (double)wq.y * xq.y;
        acc += (double)wq.z * xq.z;
        acc += (double)wq.w * xq.w;
    }
#pragma unroll
    for (int off = 32; off >= 1; off >>= 1) acc += __shfl_down(acc, off);
    return acc;
}

// ---------------------------------------------------------------------------
// Fused back half, fast path only. 256 threads/row. Candidate rank -> v32 ->
// window -> fp64 rescore -> exact rank -> scatter -> decode.
// z_sparse rows are pre-zeroed by k_gemm. ok[b]=0 defers to fallback.
// ---------------------------------------------------------------------------
__global__ __launch_bounds__(256) void k_fused(
        const float* __restrict__ x, const float* __restrict__ WT,
        const float* __restrict__ benc, const uint* __restrict__ cnt,
        const float* __restrict__ candV, const int* __restrict__ candI,
        const float* __restrict__ Wdec, const float* __restrict__ bdec,
        float* __restrict__ zsp, float* __restrict__ xrec,
        uint* __restrict__ ok) {
    int b = blockIdx.x, t = threadIdx.x;
    __shared__ float  cv[CAP];
    __shared__ int    ci[CAP];
    __shared__ float  wv[WCAP];
    __shared__ int    wi[WCAP];
    __shared__ double wex[WCAP];
    __shared__ float  x_s[DMODEL];
    __shared__ float  sv[KTOP];
    __shared__ int    si[KTOP];
    __shared__ uint   s_nw, s_v32b;

    if (t < DMODEL / 4)
        ((float4*)x_s)[t] = ((const float4*)(x + (size_t)b * DMODEL))[t];

    uint nc = cnt[b];
    int bad = (nc < KTOP) || (nc > CAP);
    if (t == 0) s_nw = 0;
    if (!bad) {
        for (uint i = t; i < nc; i += 256) {
            cv[i] = candV[(size_t)b * CAP + i];
            ci[i] = candI[(size_t)b * CAP + i];
        }
    }
    __syncthreads();

    if (!bad) {
        // rank candidates by computed value (desc, idx asc) -> find v32
        for (uint i = t; i < nc; i += 256) {
            float mv = cv[i]; int mi = ci[i];
            int rank = 0;
            for (uint j = 0; j < nc; ++j) {
                float oj = cv[j];
                rank += (oj > mv) || (oj == mv && ci[j] < mi);
            }
            if (rank == KTOP - 1) s_v32b = __float_as_uint(mv);
        }
        __syncthreads();
        float v32 = __uint_as_float(s_v32b);
        if (v32 < VGUARD) {
            bad = 1;
        } else {
            float vlo = v32 - WINDOW;
            for (uint i = t; i < nc; i += 256) {
                if (cv[i] >= vlo) {
                    uint p = atomicAdd(&s_nw, 1u);
                    if (p < WCAP) { wv[p] = cv[i]; wi[p] = ci[i]; }
                }
            }
            __syncthreads();
            if (s_nw > WCAP) bad = 1;
        }
    }
    __syncthreads();
    uint nw = s_nw;

    if (!bad) {
        // fp64 rescore: wave (t>>6) handles window items wid, wid+4, ...
        int wid = t >> 6, lane = t & 63;
        for (uint c = (uint)wid; c < nw; c += 4) {
            double acc = rescore_row(WT, x_s, wi[c], lane);
            if (lane == 0) wex[c] = acc + (double)benc[wi[c]];
        }
        __syncthreads();
        // exact ranking within window; winners = ranks 0..31
        if (t < (int)nw) {
            double my = wex[t];
            int myi = wi[t];
            int rank = 0;
            for (uint c = 0; c < nw; ++c)
                rank += (wex[c] > my) || (wex[c] == my && wi[c] < myi);
            if (rank < KTOP) { sv[rank] = wv[t]; si[rank] = myi; }
        }
    }
    __syncthreads();

    if (t == 0) ok[b] = bad ? 0u : 1u;
    if (bad) return;   // k_fallback completes this row (row zeroed by k_gemm)

    if (t < KTOP) zsp[(size_t)b * DSAE + si[t]] = sv[t];

    // decode: x_recon[b] = sum_s sv[s] * W_dec[si[s]] + b_dec
    float a0 = bdec[t], a1 = bdec[t + 256], a2 = bdec[t + 512];
#pragma unroll 8
    for (int s = 0; s < KTOP; ++s) {
        float vv = sv[s];
        const float* wr2 = Wdec + (size_t)si[s] * DMODEL + t;
        a0 += vv * wr2[0];
        a1 += vv * wr2[256];
        a2 += vv * wr2[512];
    }
    float* pr = xrec + (size_t)b * DMODEL;
    pr[t] = a0; pr[t + 256] = a1; pr[t + 512] = a2;
}

// ---------------------------------------------------------------------------
// radix select helper (64-group suffix-sum over 2048-bin histogram)
// ---------------------------------------------------------------------------
__device__ __forceinline__ uint2 radix_step(uint* hist, uint need, uint* s_res) {
    int t = threadIdx.x;
    if (t < 64) {
        uint s = 0;
#pragma unroll
        for (int j = 0; j < 32; ++j) s += hist[t * 32 + j];
        uint suf = s;
#pragma unroll
        for (int off = 1; off < 64; off <<= 1) {
            uint o = __shfl_down(suf, off);
            if (t + off < 64) suf += o;
        }
        unsigned long long m = __ballot(suf >= need);
        int L = 63 - __builtin_clzll(m);
        uint aboveg = (L == 63) ? 0u : __shfl(suf, L + 1);
        uint h = (t < 32) ? hist[L * 32 + t] : 0u;
        uint suf2 = h;
#pragma unroll
        for (int off = 1; off < 32; off <<= 1) {
            uint o = __shfl_down(suf2, off);
            if (t + off < 32) suf2 += o;
        }
        suf2 += aboveg;
        unsigned long long m2 = __ballot((t < 32) && (suf2 >= need)) & 0xffffffffull;
        int j = 31 - __builtin_clz((uint)m2);
        uint above = (j == 31) ? aboveg : __shfl(suf2, j + 1);
        if (t == 0) { s_res[0] = (uint)(L * 32 + j); s_res[1] = above; }
    }
    __syncthreads();
    uint2 r; r.x = s_res[0]; r.y = s_res[1];
    __syncthreads();
    return r;
}

// ---------------------------------------------------------------------------
// Fallback for rows where the candidate fast path failed (statistically ~0):
// full-row radix select + rescore (or ultra tie-break) + scatter + decode.
// Early-exits when ok[b]==1.
// ---------------------------------------------------------------------------
__global__ __launch_bounds__(1024) void k_fallback(
        const float* __restrict__ zpre, const float* __restrict__ x,
        const float* __restrict__ WT, const float* __restrict__ benc,
        const float* __restrict__ Wdec, const float* __restrict__ bdec,
        const uint* __restrict__ ok, float* __restrict__ zsp,
        float* __restrict__ xrec) {
    int b = blockIdx.x, t = threadIdx.x;
    if (ok[b]) return;

    __shared__ uint   hist[2048];
    __shared__ uint   s_res[2];
    __shared__ uint   s_wsum[16];
    __shared__ uint   s_total;
    __shared__ uint   s_nw;
    __shared__ float  x_s[DMODEL];
    __shared__ float  wv[WCAP];
    __shared__ int    wi[WCAP];
    __shared__ double wex[WCAP];
    __shared__ float  s_val[KTOP];
    __shared__ int    s_idx[KTOP];

    const float4* rp = (const float4*)(zpre + (size_t)b * DSAE + t * 32);
    float v[32];
#pragma unroll
    for (int i = 0; i < 8; ++i) {
        float4 q = rp[i];
        v[4 * i + 0] = fmaxf(q.x, 0.0f);
        v[4 * i + 1] = fmaxf(q.y, 0.0f);
        v[4 * i + 2] = fmaxf(q.z, 0.0f);
        v[4 * i + 3] = fmaxf(q.w, 0.0f);
    }
    if (t < DMODEL / 4) ((float4*)x_s)[t] = ((const float4*)(x + (size_t)b * DMODEL))[t];
    if (t == 0) s_nw = 0;

    hist[t] = 0; hist[t + 1024] = 0;
    __syncthreads();
#pragma unroll
    for (int i = 0; i < 32; ++i) atomicAdd(&hist[__float_as_uint(v[i]) >> 21], 1u);
    __syncthreads();
    uint2 rA = radix_step(hist, KTOP, s_res);
    uint B1 = rA.x, GA = rA.y;

    hist[t] = 0; hist[t + 1024] = 0;
    __syncthreads();
#pragma unroll
    for (int i = 0; i < 32; ++i) {
        uint bi = __float_as_uint(v[i]);
        if ((bi >> 21) == B1) atomicAdd(&hist[(bi >> 10) & 2047u], 1u);
    }
    __syncthreads();
    uint needB = KTOP - GA;
    uint2 rB = radix_step(hist, needB, s_res);
    uint B2 = rB.x, GB = rB.y;

    hist[t] = 0; hist[t + 1024] = 0;
    __syncthreads();
    uint hi21 = (B1 << 11) | B2;
#pragma unroll
    for (int i = 0; i < 32; ++i) {
        uint bi = __float_as_uint(v[i]);
        if ((bi >> 10) == hi21) atomicAdd(&hist[bi & 1023u], 1u);
    }
    __syncthreads();
    uint needC = needB - GB;
    uint2 rC = radix_step(hist, needC, s_res);
    uint tbits = (hi21 << 10) | rC.x;
    float v32b = __uint_as_float(tbits);

    int ultra = 0;
    if (v32b > 0.04f) {
        float vlo = v32b - WINDOW;
#pragma unroll
        for (int i = 0; i < 32; ++i) {
            if (v[i] >= vlo) {
                uint p = atomicAdd(&s_nw, 1u);
                if (p < WCAP) { wv[p] = v[i]; wi[p] = t * 32 + i; }
            }
        }
    }
    __syncthreads();
    uint nw = s_nw;

    if (v32b <= 0.04f || nw > WCAP) {
        // ultra-fallback: stable tiebreak on computed values
        ultra = 1;
        uint cgt = 0, ceq = 0;
#pragma unroll
        for (int i = 0; i < 32; ++i) {
            uint bi = __float_as_uint(v[i]);
            if (bi > tbits) cgt++;
            else if (bi == tbits) ceq++;
        }
        uint packed = cgt | (ceq << 16);
        int wid = t >> 6, lane = t & 63;
        uint incl = packed;
#pragma unroll
        for (int off = 1; off < 64; off <<= 1) {
            uint o = __shfl_up(incl, off);
            if (lane >= off) incl += o;
        }
        if (lane == 63) s_wsum[wid] = incl;
        __syncthreads();
        if (t == 0) {
            uint run = 0;
#pragma unroll
            for (int w2 = 0; w2 < 16; ++w2) { uint x2 = s_wsum[w2]; s_wsum[w2] = run; run += x2; }
            s_total = run;
        }
        __syncthreads();
        uint base = (incl - packed) + s_wsum[wid];
        uint grk = base & 0xffffu;
        uint erk = base >> 16;
        uint total_gt = s_total & 0xffffu;
        uint need_eq = KTOP - total_gt;
#pragma unroll
        for (int i = 0; i < 32; ++i) {
            uint bi = __float_as_uint(v[i]);
            if (bi > tbits) {
                uint s = grk++;
                s_val[s] = v[i]; s_idx[s] = t * 32 + i;
            } else if (bi == tbits) {
                uint r = erk++;
                if (r < need_eq) {
                    uint s = total_gt + r;
                    s_val[s] = v[i]; s_idx[s] = t * 32 + i;
                }
            }
        }
    }
    __syncthreads();

    if (!ultra) {
        int wid = t >> 6, lane = t & 63;
        for (uint c = (uint)wid; c < nw; c += 16) {
            double acc = rescore_row(WT, x_s, wi[c], lane);
            if (lane == 0) wex[c] = acc + (double)benc[wi[c]];
        }
        __syncthreads();
        if (t < (int)nw) {
            double my = wex[t];
            int myi = wi[t];
            int rank = 0;
            for (uint c = 0; c < nw; ++c)
                rank += (wex[c] > my) || (wex[c] == my && wi[c] < myi);
            if (rank < KTOP) { s_val[rank] = wv[t]; s_idx[rank] = myi; }
        }
        __syncthreads();
    }

    // scatter (row pre-zeroed by k_gemm) + decode
    if (t < KTOP) zsp[(size_t)b * DSAE + s_idx[t]] = s_val[t];
    if (t < DMODEL) {
        float a = bdec[t];
#pragma unroll 8
        for (int s2 = 0; s2 < KTOP; ++s2)
            a += s_val[s2] * Wdec[(size_t)s_idx[s2] * DMODEL + t];
        xrec[(size_t)b * DMODEL + t] = a;
    }
}

// ---------------------------------------------------------------------------
extern "C" void kernel_launch(void* const* d_in, const int* in_sizes, int n_in,
                              void* d_out, int out_size, void* d_ws, size_t ws_size,
                              hipStream_t stream) {
    (void)in_sizes; (void)n_in; (void)out_size; (void)ws_size;
    const float* x     = (const float*)d_in[0];
    const float* W_enc = (const float*)d_in[1];
    const float* b_enc = (const float*)d_in[2];
    const float* W_dec = (const float*)d_in[3];
    const float* b_dec = (const float*)d_in[4];

    float* xrec = (float*)d_out;                       // [4096][768]
    float* zsp  = xrec + (size_t)BATCH * DMODEL;       // [4096][32768]
    float* zpre = zsp + (size_t)BATCH * DSAE;          // [4096][32768]

    // Scratch in d_ws (~4.3 GB per harness poison fills; 176 MiB used)
    char*  ws    = (char*)d_ws;
    uint*  cnt   = (uint*)ws;                          //  16 KiB @ 0
    uint*  okf   = (uint*)(ws + (256u << 10));         //  16 KiB @ 256K
    float* candV = (float*)(ws + (1u   << 20));        //   8 MiB @ 1M
    int*   candI = (int*)  (ws + (10u  << 20));        //   8 MiB @ 10M
    f16*   xh    = (f16*)  (ws + (20u  << 20));        //   6 MiB @ 20M
    f16*   whT   = (f16*)  (ws + (28u  << 20));        //  48 MiB @ 28M
    float* WT    = (float*)(ws + (80u  << 20));        //  96 MiB @ 80M (end 176M)

    k_split_x<<<3072, 256, 0, stream>>>(x, xh, cnt);
    dim3 gw(1024, 24), tw(32, 8);
    k_split_wT<<<gw, tw, 0, stream>>>(W_enc, whT, WT);
    k_gemm<<<8192, 256, 0, stream>>>(xh, whT, b_enc, zpre, cnt, candV, candI, zsp);
    k_fused<<<4096, 256, 0, stream>>>(x, WT, b_enc, cnt, candV, candI,
                                      W_dec, b_dec, zsp, xrec, okf);
    k_fallback<<<4096, 1024, 0, stream>>>(zpre, x, WT, b_enc, W_dec, b_dec,
                                          okf, zsp, xrec);
}

// Round 19
// 605.055 us; speedup vs baseline: 1.4636x; 1.2163x over previous
//
#include <hip/hip_runtime.h>
#include <stdint.h>

#define BATCH   4096
#define DMODEL  768
#define DSAE    32768
#define KTOP    32
#define CAP     512          // candidate list capacity per row
#define WCAP    96           // exact-rescore window capacity
#define THR_CAND 2.5f        // static candidate threshold (z ~ N(0,1), v32 in [2.8,3.3])
#define WINDOW   0.08f       // rescore window half-width (> 2x max GEMM error 0.031)
#define VGUARD   2.66f       // min v32 for candidate path (= THR_CAND + 2*WINDOW)

typedef _Float16 f16;
typedef _Float16 f16x4 __attribute__((ext_vector_type(4)));
typedef _Float16 f16x8 __attribute__((ext_vector_type(8)));
typedef float    f32x4 __attribute__((ext_vector_type(4)));
typedef unsigned int uint;

// ---------------------------------------------------------------------------
// x (fp32) -> xh (fp16); also zeroes the per-row candidate counters
// ---------------------------------------------------------------------------
__global__ __launch_bounds__(256) void k_split_x(const float* __restrict__ x,
                                                 f16* __restrict__ xh,
                                                 uint* __restrict__ cnt) {
    int i = blockIdx.x * 256 + threadIdx.x;   // 786432 float4 quads
    if (i < BATCH) cnt[i] = 0;
    float4 v = ((const float4*)x)[i];
    f16x4 h;
    h[0] = (f16)v.x; h[1] = (f16)v.y; h[2] = (f16)v.z; h[3] = (f16)v.w;
    ((f16x4*)xh)[i] = h;
}

// ---------------------------------------------------------------------------
// Transpose W_enc [768][32768] -> whT fp16 [32768][768] + WT fp32 [32768][768]
// ---------------------------------------------------------------------------
__global__ __launch_bounds__(256) void k_split_wT(const float* __restrict__ W,
                                                  f16* __restrict__ whT,
                                                  float* __restrict__ WT) {
    __shared__ float T[32][33];
    int n0 = blockIdx.x * 32, k0 = blockIdx.y * 32;
    int tx = threadIdx.x, ty = threadIdx.y;   // (32, 8)
#pragma unroll
    for (int i = 0; i < 4; ++i)
        T[ty + i * 8][tx] = W[(size_t)(k0 + ty + i * 8) * DSAE + n0 + tx];
    __syncthreads();
#pragma unroll
    for (int i = 0; i < 4; ++i) {
        float v = T[tx][ty + i * 8];          // = W[k0+tx][n0+ty+i*8]
        size_t o = (size_t)(n0 + ty + i * 8) * DMODEL + k0 + tx;
        whT[o] = (f16)v;
        WT[o]  = v;
    }
}

// ---------------------------------------------------------------------------
// fp16 MFMA GEMM: z_pre = x @ W_enc + b_enc   (R15 structure = session best)
// 128x128 tile, BK=32, dbuf + counted vmcnt, 8x8-chunked per-XCD traversal.
// NON-TEMPORAL stores (via clang ext-vector f32x4 / float) for z_pre +
// z_sparse zero-fill — the ~1.1GB write stream stops allocating in L2, so
// it stops evicting the A/B staging panels; staging loads become real L2
// hits that the 1-step lookahead covers.
// ---------------------------------------------------------------------------
__device__ __forceinline__ void gl_lds16(const f16* g, f16* l) {
    __builtin_amdgcn_global_load_lds(
        (const __attribute__((address_space(1))) uint32_t*)g,
        (__attribute__((address_space(3))) uint32_t*)l,
        16, 0, 0);
}

#define BUFOFF (128 * 32)    // f16 elements per LDS buffer

__global__ __launch_bounds__(256, 3) void k_gemm(
        const f16* __restrict__ Ahg, const f16* __restrict__ Bhg,
        const float* __restrict__ benc, float* __restrict__ zpre,
        uint* __restrict__ cnt, float* __restrict__ candV,
        int* __restrict__ candI, float* __restrict__ zsp) {
    __shared__ f16 Ah[2][128][32];
    __shared__ f16 Bh[2][128][32];

    // 8192 blocks = 8 XCDs x (16 chunks of 8bm x 8bn). Bijective:
    int bid   = blockIdx.x;
    int xcd   = bid & 7;
    int k     = bid >> 3;
    int chunk = k >> 6;
    int g     = k & 63;
    int bm    = (chunk & 3) * 8 + (g & 7);
    int bn    = xcd * 32 + (chunk >> 2) * 8 + (g >> 3);
    int brow  = bm * 128, bcol = bn * 128;

    int t = threadIdx.x, lane = t & 63, w = t >> 6;
    int wr = w >> 1, wc = w & 1;

    int kk0 = (t & 3) * 8;
    const f16* pA0 = Ahg + (size_t)(brow + (t >> 2)) * DMODEL + kk0;
    const f16* pA1 = Ahg + (size_t)(brow + (t >> 2) + 64) * DMODEL + kk0;
    const f16* pB0 = Bhg + (size_t)(bcol + (t >> 2)) * DMODEL + kk0;
    const f16* pB1 = Bhg + (size_t)(bcol + (t >> 2) + 64) * DMODEL + kk0;
    f16* lA0 = &Ah[0][0][0] + t * 8;
    f16* lA1 = &Ah[0][0][0] + (t + 256) * 8;
    f16* lB0 = &Bh[0][0][0] + t * 8;
    f16* lB1 = &Bh[0][0][0] + (t + 256) * 8;

    f32x4 acc[4][4];
    f32x4 vzero = {0.0f, 0.0f, 0.0f, 0.0f};
#pragma unroll
    for (int m = 0; m < 4; ++m)
#pragma unroll
        for (int n = 0; n < 4; ++n) acc[m][n] = vzero;

    int ar = wr * 64 + (lane & 15);
    int bc = wc * 64 + (lane & 15);
    int kk = (lane >> 4) * 8;

    // prologue: stage steps 0 (buf0) and 1 (buf1) -> 8 loads in flight
    gl_lds16(pA0, lA0);
    gl_lds16(pA1, lA1);
    gl_lds16(pB0, lB0);
    gl_lds16(pB1, lB1);
    gl_lds16(pA0 + 32, lA0 + BUFOFF);
    gl_lds16(pA1 + 32, lA1 + BUFOFF);
    gl_lds16(pB0 + 32, lB0 + BUFOFF);
    gl_lds16(pB1 + 32, lB1 + BUFOFF);

    for (int ks = 0; ks < 23; ++ks) {
        int cur = ks & 1;
        asm volatile("s_waitcnt vmcnt(4)" ::: "memory");
        __builtin_amdgcn_s_barrier();          // step-ks data visible to all

        f16x8 a[4], bfr[4];
#pragma unroll
        for (int m = 0; m < 4; ++m) a[m] = *(const f16x8*)&Ah[cur][ar + m * 16][kk];
#pragma unroll
        for (int n = 0; n < 4; ++n) bfr[n] = *(const f16x8*)&Bh[cur][bc + n * 16][kk];
#pragma unroll
        for (int m = 0; m < 4; ++m)
#pragma unroll
            for (int n = 0; n < 4; ++n)
                acc[m][n] = __builtin_amdgcn_mfma_f32_16x16x32_f16(a[m], bfr[n], acc[m][n], 0, 0, 0);

        __builtin_amdgcn_s_barrier();          // all waves done reading buf[cur]
        __builtin_amdgcn_sched_barrier(0);     // keep stages below the barrier
        if (ks < 22) {
            int ko = (ks + 2) * 32;
            int bo = cur * BUFOFF;             // restage the just-freed buffer
            gl_lds16(pA0 + ko, lA0 + bo);
            gl_lds16(pA1 + ko, lA1 + bo);
            gl_lds16(pB0 + ko, lB0 + bo);
            gl_lds16(pB1 + ko, lB1 + bo);
        }
    }
    // peeled last step (ks=23, buf1)
    asm volatile("s_waitcnt vmcnt(0)" ::: "memory");
    __builtin_amdgcn_s_barrier();
    {
        f16x8 a[4], bfr[4];
#pragma unroll
        for (int m = 0; m < 4; ++m) a[m] = *(const f16x8*)&Ah[1][ar + m * 16][kk];
#pragma unroll
        for (int n = 0; n < 4; ++n) bfr[n] = *(const f16x8*)&Bh[1][bc + n * 16][kk];
#pragma unroll
        for (int m = 0; m < 4; ++m)
#pragma unroll
            for (int n = 0; n < 4; ++n)
                acc[m][n] = __builtin_amdgcn_mfma_f32_16x16x32_f16(a[m], bfr[n], acc[m][n], 0, 0, 0);
    }

    // zero-fill this block's 128x128 z_sparse tile — NON-TEMPORAL stores
    // (streaming data, never profitably cached; keeps L2 clean for staging)
    {
        f32x4 z4 = {0.0f, 0.0f, 0.0f, 0.0f};
#pragma unroll
        for (int k2 = 0; k2 < 16; ++k2) {
            int idx = t + k2 * 256;
            int row = idx >> 5, c4 = idx & 31;
            __builtin_nontemporal_store(
                z4, ((f32x4*)(zsp + (size_t)(brow + row) * DSAE + bcol)) + c4);
        }
    }

    // epilogue (C/D layout: col = lane&15, row = (lane>>4)*4 + j)
    // z_pre stores NON-TEMPORAL (pure streaming output)
#pragma unroll
    for (int n = 0; n < 4; ++n) {
        int col = bcol + wc * 64 + n * 16 + (lane & 15);
        float be = benc[col];
#pragma unroll
        for (int m = 0; m < 4; ++m) {
            int r0 = brow + wr * 64 + m * 16 + (lane >> 4) * 4;
#pragma unroll
            for (int j = 0; j < 4; ++j) {
                float zv = acc[m][n][j] + be;
                __builtin_nontemporal_store(zv, &zpre[(size_t)(r0 + j) * DSAE + col]);
                if (zv >= THR_CAND) {
                    int row = r0 + j;
                    uint p = atomicAdd(&cnt[row], 1u);
                    if (p < CAP) {
                        candV[(size_t)row * CAP + p] = zv;
                        candI[(size_t)row * CAP + p] = col;
                    }
                }
            }
        }
    }
}

// ---------------------------------------------------------------------------
// fp64 rescore of one feature row against x_s (summation tree fixed:
// lane sums elems [12*lane, 12*lane+12) in order, then shfl tree 32..1)
// ---------------------------------------------------------------------------
__device__ __forceinline__ double rescore_row(const float* __restrict__ WT,
                                              const float* __restrict__ x_s,
                                              int feat, int lane) {
    const float4* wrow = (const float4*)(WT + (size_t)feat * DMODEL) + lane * 3;
    const float4* xr = ((const float4*)x_s) + lane * 3;
    double acc = 0.0;
#pragma unroll
    for (int q = 0; q < 3; ++q) {
        float4 wq = wrow[q], xq = xr[q];
        acc += (double)wq.x * xq.x;
        acc += (double)wq.y * xq.y;
        acc += (double)wq.z * xq.z;
        acc += (double)wq.w * xq.w;
    }
#pragma unroll
    for (int off = 32; off >= 1; off >>= 1) acc += __shfl_down(acc, off);
    return acc;
}

// ---------------------------------------------------------------------------
// Fused back half, fast path only. 256 threads/row. Candidate rank -> v32 ->
// window -> fp64 rescore -> exact rank -> scatter -> decode.
// z_sparse rows are pre-zeroed by k_gemm. ok[b]=0 defers to fallback.
// ---------------------------------------------------------------------------
__global__ __launch_bounds__(256) void k_fused(
        const float* __restrict__ x, const float* __restrict__ WT,
        const float* __restrict__ benc, const uint* __restrict__ cnt,
        const float* __restrict__ candV, const int* __restrict__ candI,
        const float* __restrict__ Wdec, const float* __restrict__ bdec,
        float* __restrict__ zsp, float* __restrict__ xrec,
        uint* __restrict__ ok) {
    int b = blockIdx.x, t = threadIdx.x;
    __shared__ float  cv[CAP];
    __shared__ int    ci[CAP];
    __shared__ float  wv[WCAP];
    __shared__ int    wi[WCAP];
    __shared__ double wex[WCAP];
    __shared__ float  x_s[DMODEL];
    __shared__ float  sv[KTOP];
    __shared__ int    si[KTOP];
    __shared__ uint   s_nw, s_v32b;

    if (t < DMODEL / 4)
        ((float4*)x_s)[t] = ((const float4*)(x + (size_t)b * DMODEL))[t];

    uint nc = cnt[b];
    int bad = (nc < KTOP) || (nc > CAP);
    if (t == 0) s_nw = 0;
    if (!bad) {
        for (uint i = t; i < nc; i += 256) {
            cv[i] = candV[(size_t)b * CAP + i];
            ci[i] = candI[(size_t)b * CAP + i];
        }
    }
    __syncthreads();

    if (!bad) {
        // rank candidates by computed value (desc, idx asc) -> find v32
        for (uint i = t; i < nc; i += 256) {
            float mv = cv[i]; int mi = ci[i];
            int rank = 0;
            for (uint j = 0; j < nc; ++j) {
                float oj = cv[j];
                rank += (oj > mv) || (oj == mv && ci[j] < mi);
            }
            if (rank == KTOP - 1) s_v32b = __float_as_uint(mv);
        }
        __syncthreads();
        float v32 = __uint_as_float(s_v32b);
        if (v32 < VGUARD) {
            bad = 1;
        } else {
            float vlo = v32 - WINDOW;
            for (uint i = t; i < nc; i += 256) {
                if (cv[i] >= vlo) {
                    uint p = atomicAdd(&s_nw, 1u);
                    if (p < WCAP) { wv[p] = cv[i]; wi[p] = ci[i]; }
                }
            }
            __syncthreads();
            if (s_nw > WCAP) bad = 1;
        }
    }
    __syncthreads();
    uint nw = s_nw;

    if (!bad) {
        // fp64 rescore: wave (t>>6) handles window items wid, wid+4, ...
        int wid = t >> 6, lane = t & 63;
        for (uint c = (uint)wid; c < nw; c += 4) {
            double acc = rescore_row(WT, x_s, wi[c], lane);
            if (lane == 0) wex[c] = acc + (double)benc[wi[c]];
        }
        __syncthreads();
        // exact ranking within window; winners = ranks 0..31
        if (t < (int)nw) {
            double my = wex[t];
            int myi = wi[t];
            int rank = 0;
            for (uint c = 0; c < nw; ++c)
                rank += (wex[c] > my) || (wex[c] == my && wi[c] < myi);
            if (rank < KTOP) { sv[rank] = wv[t]; si[rank] = myi; }
        }
    }
    __syncthreads();

    if (t == 0) ok[b] = bad ? 0u : 1u;
    if (bad) return;   // k_fallback completes this row (row zeroed by k_gemm)

    if (t < KTOP) zsp[(size_t)b * DSAE + si[t]] = sv[t];

    // decode: x_recon[b] = sum_s sv[s] * W_dec[si[s]] + b_dec
    float a0 = bdec[t], a1 = bdec[t + 256], a2 = bdec[t + 512];
#pragma unroll 8
    for (int s = 0; s < KTOP; ++s) {
        float vv = sv[s];
        const float* wr2 = Wdec + (size_t)si[s] * DMODEL + t;
        a0 += vv * wr2[0];
        a1 += vv * wr2[256];
        a2 += vv * wr2[512];
    }
    float* pr = xrec + (size_t)b * DMODEL;
    pr[t] = a0; pr[t + 256] = a1; pr[t + 512] = a2;
}

// ---------------------------------------------------------------------------
// radix select helper (64-group suffix-sum over 2048-bin histogram)
// ---------------------------------------------------------------------------
__device__ __forceinline__ uint2 radix_step(uint* hist, uint need, uint* s_res) {
    int t = threadIdx.x;
    if (t < 64) {
        uint s = 0;
#pragma unroll
        for (int j = 0; j < 32; ++j) s += hist[t * 32 + j];
        uint suf = s;
#pragma unroll
        for (int off = 1; off < 64; off <<= 1) {
            uint o = __shfl_down(suf, off);
            if (t + off < 64) suf += o;
        }
        unsigned long long m = __ballot(suf >= need);
        int L = 63 - __builtin_clzll(m);
        uint aboveg = (L == 63) ? 0u : __shfl(suf, L + 1);
        uint h = (t < 32) ? hist[L * 32 + t] : 0u;
        uint suf2 = h;
#pragma unroll
        for (int off = 1; off < 32; off <<= 1) {
            uint o = __shfl_down(suf2, off);
            if (t + off < 32) suf2 += o;
        }
        suf2 += aboveg;
        unsigned long long m2 = __ballot((t < 32) && (suf2 >= need)) & 0xffffffffull;
        int j = 31 - __builtin_clz((uint)m2);
        uint above = (j == 31) ? aboveg : __shfl(suf2, j + 1);
        if (t == 0) { s_res[0] = (uint)(L * 32 + j); s_res[1] = above; }
    }
    __syncthreads();
    uint2 r; r.x = s_res[0]; r.y = s_res[1];
    __syncthreads();
    return r;
}

// ---------------------------------------------------------------------------
// Fallback for rows where the candidate fast path failed (statistically ~0):
// full-row radix select + rescore (or ultra tie-break) + scatter + decode.
// Early-exits when ok[b]==1.
// ---------------------------------------------------------------------------
__global__ __launch_bounds__(1024) void k_fallback(
        const float* __restrict__ zpre, const float* __restrict__ x,
        const float* __restrict__ WT, const float* __restrict__ benc,
        const float* __restrict__ Wdec, const float* __restrict__ bdec,
        const uint* __restrict__ ok, float* __restrict__ zsp,
        float* __restrict__ xrec) {
    int b = blockIdx.x, t = threadIdx.x;
    if (ok[b]) return;

    __shared__ uint   hist[2048];
    __shared__ uint   s_res[2];
    __shared__ uint   s_wsum[16];
    __shared__ uint   s_total;
    __shared__ uint   s_nw;
    __shared__ float  x_s[DMODEL];
    __shared__ float  wv[WCAP];
    __shared__ int    wi[WCAP];
    __shared__ double wex[WCAP];
    __shared__ float  s_val[KTOP];
    __shared__ int    s_idx[KTOP];

    const float4* rp = (const float4*)(zpre + (size_t)b * DSAE + t * 32);
    float v[32];
#pragma unroll
    for (int i = 0; i < 8; ++i) {
        float4 q = rp[i];
        v[4 * i + 0] = fmaxf(q.x, 0.0f);
        v[4 * i + 1] = fmaxf(q.y, 0.0f);
        v[4 * i + 2] = fmaxf(q.z, 0.0f);
        v[4 * i + 3] = fmaxf(q.w, 0.0f);
    }
    if (t < DMODEL / 4) ((float4*)x_s)[t] = ((const float4*)(x + (size_t)b * DMODEL))[t];
    if (t == 0) s_nw = 0;

    hist[t] = 0; hist[t + 1024] = 0;
    __syncthreads();
#pragma unroll
    for (int i = 0; i < 32; ++i) atomicAdd(&hist[__float_as_uint(v[i]) >> 21], 1u);
    __syncthreads();
    uint2 rA = radix_step(hist, KTOP, s_res);
    uint B1 = rA.x, GA = rA.y;

    hist[t] = 0; hist[t + 1024] = 0;
    __syncthreads();
#pragma unroll
    for (int i = 0; i < 32; ++i) {
        uint bi = __float_as_uint(v[i]);
        if ((bi >> 21) == B1) atomicAdd(&hist[(bi >> 10) & 2047u], 1u);
    }
    __syncthreads();
    uint needB = KTOP - GA;
    uint2 rB = radix_step(hist, needB, s_res);
    uint B2 = rB.x, GB = rB.y;

    hist[t] = 0; hist[t + 1024] = 0;
    __syncthreads();
    uint hi21 = (B1 << 11) | B2;
#pragma unroll
    for (int i = 0; i < 32; ++i) {
        uint bi = __float_as_uint(v[i]);
        if ((bi >> 10) == hi21) atomicAdd(&hist[bi & 1023u], 1u);
    }
    __syncthreads();
    uint needC = needB - GB;
    uint2 rC = radix_step(hist, needC, s_res);
    uint tbits = (hi21 << 10) | rC.x;
    float v32b = __uint_as_float(tbits);

    int ultra = 0;
    if (v32b > 0.04f) {
        float vlo = v32b - WINDOW;
#pragma unroll
        for (int i = 0; i < 32; ++i) {
            if (v[i] >= vlo) {
                uint p = atomicAdd(&s_nw, 1u);
                if (p < WCAP) { wv[p] = v[i]; wi[p] = t * 32 + i; }
            }
        }
    }
    __syncthreads();
    uint nw = s_nw;

    if (v32b <= 0.04f || nw > WCAP) {
        // ultra-fallback: stable tiebreak on computed values
        ultra = 1;
        uint cgt = 0, ceq = 0;
#pragma unroll
        for (int i = 0; i < 32; ++i) {
            uint bi = __float_as_uint(v[i]);
            if (bi > tbits) cgt++;
            else if (bi == tbits) ceq++;
        }
        uint packed = cgt | (ceq << 16);
        int wid = t >> 6, lane = t & 63;
        uint incl = packed;
#pragma unroll
        for (int off = 1; off < 64; off <<= 1) {
            uint o = __shfl_up(incl, off);
            if (lane >= off) incl += o;
        }
        if (lane == 63) s_wsum[wid] = incl;
        __syncthreads();
        if (t == 0) {
            uint run = 0;
#pragma unroll
            for (int w2 = 0; w2 < 16; ++w2) { uint x2 = s_wsum[w2]; s_wsum[w2] = run; run += x2; }
            s_total = run;
        }
        __syncthreads();
        uint base = (incl - packed) + s_wsum[wid];
        uint grk = base & 0xffffu;
        uint erk = base >> 16;
        uint total_gt = s_total & 0xffffu;
        uint need_eq = KTOP - total_gt;
#pragma unroll
        for (int i = 0; i < 32; ++i) {
            uint bi = __float_as_uint(v[i]);
            if (bi > tbits) {
                uint s = grk++;
                s_val[s] = v[i]; s_idx[s] = t * 32 + i;
            } else if (bi == tbits) {
                uint r = erk++;
                if (r < need_eq) {
                    uint s = total_gt + r;
                    s_val[s] = v[i]; s_idx[s] = t * 32 + i;
                }
            }
        }
    }
    __syncthreads();

    if (!ultra) {
        int wid = t >> 6, lane = t & 63;
        for (uint c = (uint)wid; c < nw; c += 16) {
            double acc = rescore_row(WT, x_s, wi[c], lane);
            if (lane == 0) wex[c] = acc + (double)benc[wi[c]];
        }
        __syncthreads();
        if (t < (int)nw) {
            double my = wex[t];
            int myi = wi[t];
            int rank = 0;
            for (uint c = 0; c < nw; ++c)
                rank += (wex[c] > my) || (wex[c] == my && wi[c] < myi);
            if (rank < KTOP) { s_val[rank] = wv[t]; s_idx[rank] = myi; }
        }
        __syncthreads();
    }

    // scatter (row pre-zeroed by k_gemm) + decode
    if (t < KTOP) zsp[(size_t)b * DSAE + s_idx[t]] = s_val[t];
    if (t < DMODEL) {
        float a = bdec[t];
#pragma unroll 8
        for (int s2 = 0; s2 < KTOP; ++s2)
            a += s_val[s2] * Wdec[(size_t)s_idx[s2] * DMODEL + t];
        xrec[(size_t)b * DMODEL + t] = a;
    }
}

// ---------------------------------------------------------------------------
extern "C" void kernel_launch(void* const* d_in, const int* in_sizes, int n_in,
                              void* d_out, int out_size, void* d_ws, size_t ws_size,
                              hipStream_t stream) {
    (void)in_sizes; (void)n_in; (void)out_size; (void)ws_size;
    const float* x     = (const float*)d_in[0];
    const float* W_enc = (const float*)d_in[1];
    const float* b_enc = (const float*)d_in[2];
    const float* W_dec = (const float*)d_in[3];
    const float* b_dec = (const float*)d_in[4];

    float* xrec = (float*)d_out;                       // [4096][768]
    float* zsp  = xrec + (size_t)BATCH * DMODEL;       // [4096][32768]
    float* zpre = zsp + (size_t)BATCH * DSAE;          // [4096][32768]

    // Scratch in d_ws (~4.3 GB per harness poison fills; 176 MiB used)
    char*  ws    = (char*)d_ws;
    uint*  cnt   = (uint*)ws;                          //  16 KiB @ 0
    uint*  okf   = (uint*)(ws + (256u << 10));         //  16 KiB @ 256K
    float* candV = (float*)(ws + (1u   << 20));        //   8 MiB @ 1M
    int*   candI = (int*)  (ws + (10u  << 20));        //   8 MiB @ 10M
    f16*   xh    = (f16*)  (ws + (20u  << 20));        //   6 MiB @ 20M
    f16*   whT   = (f16*)  (ws + (28u  << 20));        //  48 MiB @ 28M
    float* WT    = (float*)(ws + (80u  << 20));        //  96 MiB @ 80M (end 176M)

    k_split_x<<<3072, 256, 0, stream>>>(x, xh, cnt);
    dim3 gw(1024, 24), tw(32, 8);
    k_split_wT<<<gw, tw, 0, stream>>>(W_enc, whT, WT);
    k_gemm<<<8192, 256, 0, stream>>>(xh, whT, b_enc, zpre, cnt, candV, candI, zsp);
    k_fused<<<4096, 256, 0, stream>>>(x, WT, b_enc, cnt, candV, candI,
                                      W_dec, b_dec, zsp, xrec, okf);
    k_fallback<<<4096, 1024, 0, stream>>>(zpre, x, WT, b_enc, W_dec, b_dec,
                                          okf, zsp, xrec);
}

// Round 20
// 599.992 us; speedup vs baseline: 1.4760x; 1.0084x over previous
//
#include <hip/hip_runtime.h>
#include <stdint.h>

#define BATCH   4096
#define DMODEL  768
#define DSAE    32768
#define KTOP    32
#define CAP     512          // candidate list capacity per row
#define WCAP    96           // exact-rescore window capacity
#define THR_CAND 2.5f        // static candidate threshold (z ~ N(0,1), v32 in [2.8,3.3])
#define WINDOW   0.08f       // rescore window half-width (> 2x max GEMM error 0.031)
#define VGUARD   2.66f       // min v32 for candidate path (= THR_CAND + 2*WINDOW)

typedef _Float16 f16;
typedef _Float16 f16x4 __attribute__((ext_vector_type(4)));
typedef _Float16 f16x8 __attribute__((ext_vector_type(8)));
typedef float    f32x4 __attribute__((ext_vector_type(4)));
typedef unsigned int uint;

// ---------------------------------------------------------------------------
// x (fp32) -> xh (fp16); also zeroes the per-row candidate counters
// ---------------------------------------------------------------------------
__global__ __launch_bounds__(256) void k_split_x(const float* __restrict__ x,
                                                 f16* __restrict__ xh,
                                                 uint* __restrict__ cnt) {
    int i = blockIdx.x * 256 + threadIdx.x;   // 786432 float4 quads
    if (i < BATCH) cnt[i] = 0;
    float4 v = ((const float4*)x)[i];
    f16x4 h;
    h[0] = (f16)v.x; h[1] = (f16)v.y; h[2] = (f16)v.z; h[3] = (f16)v.w;
    ((f16x4*)xh)[i] = h;
}

// ---------------------------------------------------------------------------
// Transpose W_enc [768][32768] -> whT fp16 [32768][768] + WT fp32 [32768][768]
// ---------------------------------------------------------------------------
__global__ __launch_bounds__(256) void k_split_wT(const float* __restrict__ W,
                                                  f16* __restrict__ whT,
                                                  float* __restrict__ WT) {
    __shared__ float T[32][33];
    int n0 = blockIdx.x * 32, k0 = blockIdx.y * 32;
    int tx = threadIdx.x, ty = threadIdx.y;   // (32, 8)
#pragma unroll
    for (int i = 0; i < 4; ++i)
        T[ty + i * 8][tx] = W[(size_t)(k0 + ty + i * 8) * DSAE + n0 + tx];
    __syncthreads();
#pragma unroll
    for (int i = 0; i < 4; ++i) {
        float v = T[tx][ty + i * 8];          // = W[k0+tx][n0+ty+i*8]
        size_t o = (size_t)(n0 + ty + i * 8) * DMODEL + k0 + tx;
        whT[o] = (f16)v;
        WT[o]  = v;
    }
}

// ---------------------------------------------------------------------------
// fp16 MFMA GEMM: z_pre = x @ W_enc + b_enc   (R19 structure + (256,4))
// 128x128 tile, BK=32, dbuf + counted vmcnt, 8x8-chunked per-XCD traversal,
// NON-TEMPORAL stores for z_pre + z_sparse zero-fill (keeps L2 clean for
// staging panels — R19's +17%). (256,4): 4 blocks/CU for extra TLP to hide
// the residual L2-hit staging latency (VGPR budget 128 >= used, no spill).
// ---------------------------------------------------------------------------
__device__ __forceinline__ void gl_lds16(const f16* g, f16* l) {
    __builtin_amdgcn_global_load_lds(
        (const __attribute__((address_space(1))) uint32_t*)g,
        (__attribute__((address_space(3))) uint32_t*)l,
        16, 0, 0);
}

#define BUFOFF (128 * 32)    // f16 elements per LDS buffer

__global__ __launch_bounds__(256, 4) void k_gemm(
        const f16* __restrict__ Ahg, const f16* __restrict__ Bhg,
        const float* __restrict__ benc, float* __restrict__ zpre,
        uint* __restrict__ cnt, float* __restrict__ candV,
        int* __restrict__ candI, float* __restrict__ zsp) {
    __shared__ f16 Ah[2][128][32];
    __shared__ f16 Bh[2][128][32];

    // 8192 blocks = 8 XCDs x (16 chunks of 8bm x 8bn). Bijective:
    int bid   = blockIdx.x;
    int xcd   = bid & 7;
    int k     = bid >> 3;
    int chunk = k >> 6;
    int g     = k & 63;
    int bm    = (chunk & 3) * 8 + (g & 7);
    int bn    = xcd * 32 + (chunk >> 2) * 8 + (g >> 3);
    int brow  = bm * 128, bcol = bn * 128;

    int t = threadIdx.x, lane = t & 63, w = t >> 6;
    int wr = w >> 1, wc = w & 1;

    int kk0 = (t & 3) * 8;
    const f16* pA0 = Ahg + (size_t)(brow + (t >> 2)) * DMODEL + kk0;
    const f16* pA1 = Ahg + (size_t)(brow + (t >> 2) + 64) * DMODEL + kk0;
    const f16* pB0 = Bhg + (size_t)(bcol + (t >> 2)) * DMODEL + kk0;
    const f16* pB1 = Bhg + (size_t)(bcol + (t >> 2) + 64) * DMODEL + kk0;
    f16* lA0 = &Ah[0][0][0] + t * 8;
    f16* lA1 = &Ah[0][0][0] + (t + 256) * 8;
    f16* lB0 = &Bh[0][0][0] + t * 8;
    f16* lB1 = &Bh[0][0][0] + (t + 256) * 8;

    f32x4 acc[4][4];
    f32x4 vzero = {0.0f, 0.0f, 0.0f, 0.0f};
#pragma unroll
    for (int m = 0; m < 4; ++m)
#pragma unroll
        for (int n = 0; n < 4; ++n) acc[m][n] = vzero;

    int ar = wr * 64 + (lane & 15);
    int bc = wc * 64 + (lane & 15);
    int kk = (lane >> 4) * 8;

    // prologue: stage steps 0 (buf0) and 1 (buf1) -> 8 loads in flight
    gl_lds16(pA0, lA0);
    gl_lds16(pA1, lA1);
    gl_lds16(pB0, lB0);
    gl_lds16(pB1, lB1);
    gl_lds16(pA0 + 32, lA0 + BUFOFF);
    gl_lds16(pA1 + 32, lA1 + BUFOFF);
    gl_lds16(pB0 + 32, lB0 + BUFOFF);
    gl_lds16(pB1 + 32, lB1 + BUFOFF);

    for (int ks = 0; ks < 23; ++ks) {
        int cur = ks & 1;
        asm volatile("s_waitcnt vmcnt(4)" ::: "memory");
        __builtin_amdgcn_s_barrier();          // step-ks data visible to all

        f16x8 a[4], bfr[4];
#pragma unroll
        for (int m = 0; m < 4; ++m) a[m] = *(const f16x8*)&Ah[cur][ar + m * 16][kk];
#pragma unroll
        for (int n = 0; n < 4; ++n) bfr[n] = *(const f16x8*)&Bh[cur][bc + n * 16][kk];
#pragma unroll
        for (int m = 0; m < 4; ++m)
#pragma unroll
            for (int n = 0; n < 4; ++n)
                acc[m][n] = __builtin_amdgcn_mfma_f32_16x16x32_f16(a[m], bfr[n], acc[m][n], 0, 0, 0);

        __builtin_amdgcn_s_barrier();          // all waves done reading buf[cur]
        __builtin_amdgcn_sched_barrier(0);     // keep stages below the barrier
        if (ks < 22) {
            int ko = (ks + 2) * 32;
            int bo = cur * BUFOFF;             // restage the just-freed buffer
            gl_lds16(pA0 + ko, lA0 + bo);
            gl_lds16(pA1 + ko, lA1 + bo);
            gl_lds16(pB0 + ko, lB0 + bo);
            gl_lds16(pB1 + ko, lB1 + bo);
        }
    }
    // peeled last step (ks=23, buf1)
    asm volatile("s_waitcnt vmcnt(0)" ::: "memory");
    __builtin_amdgcn_s_barrier();
    {
        f16x8 a[4], bfr[4];
#pragma unroll
        for (int m = 0; m < 4; ++m) a[m] = *(const f16x8*)&Ah[1][ar + m * 16][kk];
#pragma unroll
        for (int n = 0; n < 4; ++n) bfr[n] = *(const f16x8*)&Bh[1][bc + n * 16][kk];
#pragma unroll
        for (int m = 0; m < 4; ++m)
#pragma unroll
            for (int n = 0; n < 4; ++n)
                acc[m][n] = __builtin_amdgcn_mfma_f32_16x16x32_f16(a[m], bfr[n], acc[m][n], 0, 0, 0);
    }

    // zero-fill this block's 128x128 z_sparse tile — NON-TEMPORAL stores
    {
        f32x4 z4 = {0.0f, 0.0f, 0.0f, 0.0f};
#pragma unroll
        for (int k2 = 0; k2 < 16; ++k2) {
            int idx = t + k2 * 256;
            int row = idx >> 5, c4 = idx & 31;
            __builtin_nontemporal_store(
                z4, ((f32x4*)(zsp + (size_t)(brow + row) * DSAE + bcol)) + c4);
        }
    }

    // epilogue (C/D layout: col = lane&15, row = (lane>>4)*4 + j)
    // z_pre stores NON-TEMPORAL (pure streaming output)
#pragma unroll
    for (int n = 0; n < 4; ++n) {
        int col = bcol + wc * 64 + n * 16 + (lane & 15);
        float be = benc[col];
#pragma unroll
        for (int m = 0; m < 4; ++m) {
            int r0 = brow + wr * 64 + m * 16 + (lane >> 4) * 4;
#pragma unroll
            for (int j = 0; j < 4; ++j) {
                float zv = acc[m][n][j] + be;
                __builtin_nontemporal_store(zv, &zpre[(size_t)(r0 + j) * DSAE + col]);
                if (zv >= THR_CAND) {
                    int row = r0 + j;
                    uint p = atomicAdd(&cnt[row], 1u);
                    if (p < CAP) {
                        candV[(size_t)row * CAP + p] = zv;
                        candI[(size_t)row * CAP + p] = col;
                    }
                }
            }
        }
    }
}

// ---------------------------------------------------------------------------
// fp64 rescore of one feature row against x_s (summation tree fixed:
// lane sums elems [12*lane, 12*lane+12) in order, then shfl tree 32..1)
// ---------------------------------------------------------------------------
__device__ __forceinline__ double rescore_row(const float* __restrict__ WT,
                                              const float* __restrict__ x_s,
                                              int feat, int lane) {
    const float4* wrow = (const float4*)(WT + (size_t)feat * DMODEL) + lane * 3;
    const float4* xr = ((const float4*)x_s) + lane * 3;
    double acc = 0.0;
#pragma unroll
    for (int q = 0; q < 3; ++q) {
        float4 wq = wrow[q], xq = xr[q];
        acc += (double)wq.x * xq.x;
        acc += (double)wq.y * xq.y;
        acc += (double)wq.z * xq.z;
        acc += (double)wq.w * xq.w;
    }
#pragma unroll
    for (int off = 32; off >= 1; off >>= 1) acc += __shfl_down(acc, off);
    return acc;
}

// ---------------------------------------------------------------------------
// Fused back half, fast path only. 256 threads/row. Candidate rank -> v32 ->
// window -> fp64 rescore -> exact rank -> scatter -> decode.
// z_sparse rows are pre-zeroed by k_gemm. ok[b]=0 defers to fallback.
// ---------------------------------------------------------------------------
__global__ __launch_bounds__(256) void k_fused(
        const float* __restrict__ x, const float* __restrict__ WT,
        const float* __restrict__ benc, const uint* __restrict__ cnt,
        const float* __restrict__ candV, const int* __restrict__ candI,
        const float* __restrict__ Wdec, const float* __restrict__ bdec,
        float* __restrict__ zsp, float* __restrict__ xrec,
        uint* __restrict__ ok) {
    int b = blockIdx.x, t = threadIdx.x;
    __shared__ float  cv[CAP];
    __shared__ int    ci[CAP];
    __shared__ float  wv[WCAP];
    __shared__ int    wi[WCAP];
    __shared__ double wex[WCAP];
    __shared__ float  x_s[DMODEL];
    __shared__ float  sv[KTOP];
    __shared__ int    si[KTOP];
    __shared__ uint   s_nw, s_v32b;

    if (t < DMODEL / 4)
        ((float4*)x_s)[t] = ((const float4*)(x + (size_t)b * DMODEL))[t];

    uint nc = cnt[b];
    int bad = (nc < KTOP) || (nc > CAP);
    if (t == 0) s_nw = 0;
    if (!bad) {
        for (uint i = t; i < nc; i += 256) {
            cv[i] = candV[(size_t)b * CAP + i];
            ci[i] = candI[(size_t)b * CAP + i];
        }
    }
    __syncthreads();

    if (!bad) {
        // rank candidates by computed value (desc, idx asc) -> find v32
        for (uint i = t; i < nc; i += 256) {
            float mv = cv[i]; int mi = ci[i];
            int rank = 0;
            for (uint j = 0; j < nc; ++j) {
                float oj = cv[j];
                rank += (oj > mv) || (oj == mv && ci[j] < mi);
            }
            if (rank == KTOP - 1) s_v32b = __float_as_uint(mv);
        }
        __syncthreads();
        float v32 = __uint_as_float(s_v32b);
        if (v32 < VGUARD) {
            bad = 1;
        } else {
            float vlo = v32 - WINDOW;
            for (uint i = t; i < nc; i += 256) {
                if (cv[i] >= vlo) {
                    uint p = atomicAdd(&s_nw, 1u);
                    if (p < WCAP) { wv[p] = cv[i]; wi[p] = ci[i]; }
                }
            }
            __syncthreads();
            if (s_nw > WCAP) bad = 1;
        }
    }
    __syncthreads();
    uint nw = s_nw;

    if (!bad) {
        // fp64 rescore: wave (t>>6) handles window items wid, wid+4, ...
        int wid = t >> 6, lane = t & 63;
        for (uint c = (uint)wid; c < nw; c += 4) {
            double acc = rescore_row(WT, x_s, wi[c], lane);
            if (lane == 0) wex[c] = acc + (double)benc[wi[c]];
        }
        __syncthreads();
        // exact ranking within window; winners = ranks 0..31
        if (t < (int)nw) {
            double my = wex[t];
            int myi = wi[t];
            int rank = 0;
            for (uint c = 0; c < nw; ++c)
                rank += (wex[c] > my) || (wex[c] == my && wi[c] < myi);
            if (rank < KTOP) { sv[rank] = wv[t]; si[rank] = myi; }
        }
    }
    __syncthreads();

    if (t == 0) ok[b] = bad ? 0u : 1u;
    if (bad) return;   // k_fallback completes this row (row zeroed by k_gemm)

    if (t < KTOP) zsp[(size_t)b * DSAE + si[t]] = sv[t];

    // decode: x_recon[b] = sum_s sv[s] * W_dec[si[s]] + b_dec
    float a0 = bdec[t], a1 = bdec[t + 256], a2 = bdec[t + 512];
#pragma unroll 8
    for (int s = 0; s < KTOP; ++s) {
        float vv = sv[s];
        const float* wr2 = Wdec + (size_t)si[s] * DMODEL + t;
        a0 += vv * wr2[0];
        a1 += vv * wr2[256];
        a2 += vv * wr2[512];
    }
    float* pr = xrec + (size_t)b * DMODEL;
    pr[t] = a0; pr[t + 256] = a1; pr[t + 512] = a2;
}

// ---------------------------------------------------------------------------
// radix select helper (64-group suffix-sum over 2048-bin histogram)
// ---------------------------------------------------------------------------
__device__ __forceinline__ uint2 radix_step(uint* hist, uint need, uint* s_res) {
    int t = threadIdx.x;
    if (t < 64) {
        uint s = 0;
#pragma unroll
        for (int j = 0; j < 32; ++j) s += hist[t * 32 + j];
        uint suf = s;
#pragma unroll
        for (int off = 1; off < 64; off <<= 1) {
            uint o = __shfl_down(suf, off);
            if (t + off < 64) suf += o;
        }
        unsigned long long m = __ballot(suf >= need);
        int L = 63 - __builtin_clzll(m);
        uint aboveg = (L == 63) ? 0u : __shfl(suf, L + 1);
        uint h = (t < 32) ? hist[L * 32 + t] : 0u;
        uint suf2 = h;
#pragma unroll
        for (int off = 1; off < 32; off <<= 1) {
            uint o = __shfl_down(suf2, off);
            if (t + off < 32) suf2 += o;
        }
        suf2 += aboveg;
        unsigned long long m2 = __ballot((t < 32) && (suf2 >= need)) & 0xffffffffull;
        int j = 31 - __builtin_clz((uint)m2);
        uint above = (j == 31) ? aboveg : __shfl(suf2, j + 1);
        if (t == 0) { s_res[0] = (uint)(L * 32 + j); s_res[1] = above; }
    }
    __syncthreads();
    uint2 r; r.x = s_res[0]; r.y = s_res[1];
    __syncthreads();
    return r;
}

// ---------------------------------------------------------------------------
// Fallback for rows where the candidate fast path failed (statistically ~0):
// full-row radix select + rescore (or ultra tie-break) + scatter + decode.
// Early-exits when ok[b]==1.
// ---------------------------------------------------------------------------
__global__ __launch_bounds__(1024) void k_fallback(
        const float* __restrict__ zpre, const float* __restrict__ x,
        const float* __restrict__ WT, const float* __restrict__ benc,
        const float* __restrict__ Wdec, const float* __restrict__ bdec,
        const uint* __restrict__ ok, float* __restrict__ zsp,
        float* __restrict__ xrec) {
    int b = blockIdx.x, t = threadIdx.x;
    if (ok[b]) return;

    __shared__ uint   hist[2048];
    __shared__ uint   s_res[2];
    __shared__ uint   s_wsum[16];
    __shared__ uint   s_total;
    __shared__ uint   s_nw;
    __shared__ float  x_s[DMODEL];
    __shared__ float  wv[WCAP];
    __shared__ int    wi[WCAP];
    __shared__ double wex[WCAP];
    __shared__ float  s_val[KTOP];
    __shared__ int    s_idx[KTOP];

    const float4* rp = (const float4*)(zpre + (size_t)b * DSAE + t * 32);
    float v[32];
#pragma unroll
    for (int i = 0; i < 8; ++i) {
        float4 q = rp[i];
        v[4 * i + 0] = fmaxf(q.x, 0.0f);
        v[4 * i + 1] = fmaxf(q.y, 0.0f);
        v[4 * i + 2] = fmaxf(q.z, 0.0f);
        v[4 * i + 3] = fmaxf(q.w, 0.0f);
    }
    if (t < DMODEL / 4) ((float4*)x_s)[t] = ((const float4*)(x + (size_t)b * DMODEL))[t];
    if (t == 0) s_nw = 0;

    hist[t] = 0; hist[t + 1024] = 0;
    __syncthreads();
#pragma unroll
    for (int i = 0; i < 32; ++i) atomicAdd(&hist[__float_as_uint(v[i]) >> 21], 1u);
    __syncthreads();
    uint2 rA = radix_step(hist, KTOP, s_res);
    uint B1 = rA.x, GA = rA.y;

    hist[t] = 0; hist[t + 1024] = 0;
    __syncthreads();
#pragma unroll
    for (int i = 0; i < 32; ++i) {
        uint bi = __float_as_uint(v[i]);
        if ((bi >> 21) == B1) atomicAdd(&hist[(bi >> 10) & 2047u], 1u);
    }
    __syncthreads();
    uint needB = KTOP - GA;
    uint2 rB = radix_step(hist, needB, s_res);
    uint B2 = rB.x, GB = rB.y;

    hist[t] = 0; hist[t + 1024] = 0;
    __syncthreads();
    uint hi21 = (B1 << 11) | B2;
#pragma unroll
    for (int i = 0; i < 32; ++i) {
        uint bi = __float_as_uint(v[i]);
        if ((bi >> 10) == hi21) atomicAdd(&hist[bi & 1023u], 1u);
    }
    __syncthreads();
    uint needC = needB - GB;
    uint2 rC = radix_step(hist, needC, s_res);
    uint tbits = (hi21 << 10) | rC.x;
    float v32b = __uint_as_float(tbits);

    int ultra = 0;
    if (v32b > 0.04f) {
        float vlo = v32b - WINDOW;
#pragma unroll
        for (int i = 0; i < 32; ++i) {
            if (v[i] >= vlo) {
                uint p = atomicAdd(&s_nw, 1u);
                if (p < WCAP) { wv[p] = v[i]; wi[p] = t * 32 + i; }
            }
        }
    }
    __syncthreads();
    uint nw = s_nw;

    if (v32b <= 0.04f || nw > WCAP) {
        // ultra-fallback: stable tiebreak on computed values
        ultra = 1;
        uint cgt = 0, ceq = 0;
#pragma unroll
        for (int i = 0; i < 32; ++i) {
            uint bi = __float_as_uint(v[i]);
            if (bi > tbits) cgt++;
            else if (bi == tbits) ceq++;
        }
        uint packed = cgt | (ceq << 16);
        int wid = t >> 6, lane = t & 63;
        uint incl = packed;
#pragma unroll
        for (int off = 1; off < 64; off <<= 1) {
            uint o = __shfl_up(incl, off);
            if (lane >= off) incl += o;
        }
        if (lane == 63) s_wsum[wid] = incl;
        __syncthreads();
        if (t == 0) {
            uint run = 0;
#pragma unroll
            for (int w2 = 0; w2 < 16; ++w2) { uint x2 = s_wsum[w2]; s_wsum[w2] = run; run += x2; }
            s_total = run;
        }
        __syncthreads();
        uint base = (incl - packed) + s_wsum[wid];
        uint grk = base & 0xffffu;
        uint erk = base >> 16;
        uint total_gt = s_total & 0xffffu;
        uint need_eq = KTOP - total_gt;
#pragma unroll
        for (int i = 0; i < 32; ++i) {
            uint bi = __float_as_uint(v[i]);
            if (bi > tbits) {
                uint s = grk++;
                s_val[s] = v[i]; s_idx[s] = t * 32 + i;
            } else if (bi == tbits) {
                uint r = erk++;
                if (r < need_eq) {
                    uint s = total_gt + r;
                    s_val[s] = v[i]; s_idx[s] = t * 32 + i;
                }
            }
        }
    }
    __syncthreads();

    if (!ultra) {
        int wid = t >> 6, lane = t & 63;
        for (uint c = (uint)wid; c < nw; c += 16) {
            double acc = rescore_row(WT, x_s, wi[c], lane);
            if (lane == 0) wex[c] = acc + (double)benc[wi[c]];
        }
        __syncthreads();
        if (t < (int)nw) {
            double my = wex[t];
            int myi = wi[t];
            int rank = 0;
            for (uint c = 0; c < nw; ++c)
                rank += (wex[c] > my) || (wex[c] == my && wi[c] < myi);
            if (rank < KTOP) { s_val[rank] = wv[t]; s_idx[rank] = myi; }
        }
        __syncthreads();
    }

    // scatter (row pre-zeroed by k_gemm) + decode
    if (t < KTOP) zsp[(size_t)b * DSAE + s_idx[t]] = s_val[t];
    if (t < DMODEL) {
        float a = bdec[t];
#pragma unroll 8
        for (int s2 = 0; s2 < KTOP; ++s2)
            a += s_val[s2] * Wdec[(size_t)s_idx[s2] * DMODEL + t];
        xrec[(size_t)b * DMODEL + t] = a;
    }
}

// ---------------------------------------------------------------------------
extern "C" void kernel_launch(void* const* d_in, const int* in_sizes, int n_in,
                              void* d_out, int out_size, void* d_ws, size_t ws_size,
                              hipStream_t stream) {
    (void)in_sizes; (void)n_in; (void)out_size; (void)ws_size;
    const float* x     = (const float*)d_in[0];
    const float* W_enc = (const float*)d_in[1];
    const float* b_enc = (const float*)d_in[2];
    const float* W_dec = (const float*)d_in[3];
    const float* b_dec = (const float*)d_in[4];

    float* xrec = (float*)d_out;                       // [4096][768]
    float* zsp  = xrec + (size_t)BATCH * DMODEL;       // [4096][32768]
    float* zpre = zsp + (size_t)BATCH * DSAE;          // [4096][32768]

    // Scratch in d_ws (~4.3 GB per harness poison fills; 176 MiB used)
    char*  ws    = (char*)d_ws;
    uint*  cnt   = (uint*)ws;                          //  16 KiB @ 0
    uint*  okf   = (uint*)(ws + (256u << 10));         //  16 KiB @ 256K
    float* candV = (float*)(ws + (1u   << 20));        //   8 MiB @ 1M
    int*   candI = (int*)  (ws + (10u  << 20));        //   8 MiB @ 10M
    f16*   xh    = (f16*)  (ws + (20u  << 20));        //   6 MiB @ 20M
    f16*   whT   = (f16*)  (ws + (28u  << 20));        //  48 MiB @ 28M
    float* WT    = (float*)(ws + (80u  << 20));        //  96 MiB @ 80M (end 176M)

    k_split_x<<<3072, 256, 0, stream>>>(x, xh, cnt);
    dim3 gw(1024, 24), tw(32, 8);
    k_split_wT<<<gw, tw, 0, stream>>>(W_enc, whT, WT);
    k_gemm<<<8192, 256, 0, stream>>>(xh, whT, b_enc, zpre, cnt, candV, candI, zsp);
    k_fused<<<4096, 256, 0, stream>>>(x, WT, b_enc, cnt, candV, candI,
                                      W_dec, b_dec, zsp, xrec, okf);
    k_fallback<<<4096, 1024, 0, stream>>>(zpre, x, WT, b_enc, W_dec, b_dec,
                                          okf, zsp, xrec);
}